// Round 9
// baseline (226.504 us; speedup 1.0000x reference)
//
#include <hip/hip_runtime.h>
#include <stdint.h>

#define B_    4
#define CIN   32
#define NN    1024
#define SS    32
#define COUT  64
#define CSP   64
#define EPSV  1e-5f

typedef __attribute__((ext_vector_type(8))) short bfrag;   // 8 bf16 in 4 VGPRs
typedef __attribute__((ext_vector_type(4))) float facc;    // MFMA accumulator

__device__ __forceinline__ uint32_t f2b_rne(float f) {
    uint32_t x = __float_as_uint(f);
    return (x + 0x7fffu + ((x >> 16) & 1u)) >> 16;
}
__device__ __forceinline__ float bfu(uint32_t v) { return __uint_as_float(v << 16); }
__device__ __forceinline__ float bfh(uint32_t v) { return __uint_as_float(v & 0xffff0000u); }

// ---------- graph prep ----------
__global__ void detect_kernel(const int* __restrict__ ei, int* __restrict__ flag) {
    if (threadIdx.x == 0) {
        int nz = 0;
        for (int i = 1; i < 257; i += 2) nz |= ei[i];
        *flag = (nz == 0) ? 1 : 0;   // 1 => int64 layout
    }
}

__global__ void deg_count_kernel(const int* __restrict__ ei, int E,
                                 const int* __restrict__ flag, int* __restrict__ deg) {
    int e = blockIdx.x * 256 + threadIdx.x;
    int i64 = *flag;
    if (e < E) {
        int d = i64 ? ei[2 * (E + e)] : ei[E + e];
        atomicAdd(&deg[d], 1);
    }
}

__global__ __launch_bounds__(1024) void scan_kernel(
    const int* __restrict__ deg, int* __restrict__ row_ptr, float* __restrict__ dinv) {
    __shared__ int sb[NN];
    int t = threadIdx.x;
    int v = deg[t];
    sb[t] = v;
    __syncthreads();
    for (int off = 1; off < NN; off <<= 1) {
        int tmp = (t >= off) ? sb[t - off] : 0;
        __syncthreads();
        sb[t] += tmp;
        __syncthreads();
    }
    row_ptr[t] = sb[t] - v;                 // exclusive scan
    if (t == NN - 1) row_ptr[NN] = sb[t];
    dinv[t] = rsqrtf((float)(v + 1));       // +1 self-loop
}

// Packed edge descriptors: {srcn, dinv[srcn]}
__global__ void csr_fill_kernel(const int* __restrict__ ei, int E,
                                const int* __restrict__ flag,
                                const int* __restrict__ row_ptr, int* __restrict__ cursor,
                                const float* __restrict__ dinv, int2* __restrict__ edata) {
    int e = blockIdx.x * 256 + threadIdx.x;
    int i64 = *flag;
    if (e < E) {
        int s = i64 ? ei[2 * e] : ei[e];
        int d = i64 ? ei[2 * (E + e)] : ei[E + e];
        int pos = atomicAdd(&cursor[d], 1);
        edata[row_ptr[d] + pos] = make_int2(s, __float_as_int(dinv[s]));
    }
}

// ---------- one-shot W2 fragment pack: hi/lo bf16 MFMA B-fragments, per-lane ----
__global__ void w2pack_kernel(const float* __restrict__ W2,
                              uint32_t* __restrict__ wpkH, uint32_t* __restrict__ wpkL) {
    int flat = blockIdx.x * 256 + threadIdx.x;   // 6*256 = 1536 = 24*64
    int lane = flat & 63, fi = flat >> 6;
    int kh = fi & 1, q = fi >> 1;
    int tap = q % 3, cc = q / 3;
    int ct = cc & 1, cb2 = cc >> 1;
    int cout = cb2 * 32 + ct * 16 + (lane & 15);
    int cbase = kh * 32 + (lane >> 4) * 8;
    const float* wp = W2 + ((size_t)cout * 64 + cbase) * 3 + tap;
    uint32_t h[8], l[8];
#pragma unroll
    for (int j = 0; j < 8; j++) {
        float w = wp[3 * j];
        uint32_t hb = f2b_rne(w);
        uint32_t lb = f2b_rne(w - bfu(hb));
        h[j] = hb; l[j] = lb;
    }
    uint4 H = {h[0] | (h[1] << 16), h[2] | (h[3] << 16),
               h[4] | (h[5] << 16), h[6] | (h[7] << 16)};
    uint4 L = {l[0] | (l[1] << 16), l[2] | (l[3] << 16),
               l[4] | (l[5] << 16), l[6] | (l[7] << 16)};
    ((uint4*)wpkH)[flat] = H;
    ((uint4*)wpkL)[flat] = L;
}

// ---------- one-shot W1 fragment pack (conv1 B-operand): 12 frags x 64 lanes ----
__global__ void w1pack_kernel(const float* __restrict__ W1,
                              uint32_t* __restrict__ wpk1H, uint32_t* __restrict__ wpk1L) {
    int flat = blockIdx.x * 256 + threadIdx.x;   // 3*256 = 768 = 12*64
    int lane = flat & 63, fi = flat >> 6;
    int tap = fi % 3, cc = fi / 3;
    int ct = cc & 1, cb2 = cc >> 1;
    int cout = cb2 * 32 + ct * 16 + (lane & 15);
    int k0 = (lane >> 4) * 8;
    const float* wp = W1 + (size_t)cout * 96 + k0 * 3 + tap;  // W1[cout][cin][3]
    uint32_t h[8], l[8];
#pragma unroll
    for (int j = 0; j < 8; j++) {
        float w = wp[3 * j];
        uint32_t hb = f2b_rne(w);
        uint32_t lb = f2b_rne(w - bfu(hb));
        h[j] = hb; l[j] = lb;
    }
    uint4 H = {h[0] | (h[1] << 16), h[2] | (h[3] << 16),
               h[4] | (h[5] << 16), h[6] | (h[7] << 16)};
    uint4 L = {l[0] | (l[1] << 16), l[2] | (l[3] << 16),
               l[4] | (l[5] << 16), l[6] | (l[7] << 16)};
    ((uint4*)wpk1H)[flat] = H;
    ((uint4*)wpk1L)[flat] = L;
}

// ---------- one-shot Wg fragment pack (bn1 A-operand, Wg^T): 8 frags x 64 lanes --
__global__ void wgpack_kernel(const float* __restrict__ Wg,
                              uint32_t* __restrict__ wgpH, uint32_t* __restrict__ wgpL) {
    int flat = blockIdx.x * 256 + threadIdx.x;   // 2*256 = 512 = 8*64
    int lane = flat & 63, fi = flat >> 6;
    int kh = fi & 1, dt = fi >> 1;
    int d = dt * 16 + (lane & 15);
    int c0 = kh * 32 + (lane >> 4) * 8;
    const float* wp = Wg + (size_t)c0 * CSP + d;
    uint32_t h[8], l[8];
#pragma unroll
    for (int j = 0; j < 8; j++) {
        float w = wp[(size_t)j * CSP];
        uint32_t hb = f2b_rne(w);
        uint32_t lb = f2b_rne(w - bfu(hb));
        h[j] = hb; l[j] = lb;
    }
    uint4 H = {h[0] | (h[1] << 16), h[2] | (h[3] << 16),
               h[4] | (h[5] << 16), h[6] | (h[7] << 16)};
    uint4 L = {l[0] | (l[1] << 16), l[2] | (l[3] << 16),
               l[4] | (l[5] << 16), l[6] | (l[7] << 16)};
    ((uint4*)wgpH)[flat] = H;
    ((uint4*)wgpL)[flat] = L;
}

// ---------- conv1 via MFMA: same recipe as conv2_mfma (R6 verified) ----------
__global__ __launch_bounds__(256, 2) void conv1_mfma_kernel(
    const float* __restrict__ x, const uint32_t* __restrict__ wpk1H,
    const uint32_t* __restrict__ wpk1L, const float* __restrict__ b1,
    float* __restrict__ h_pre, float* __restrict__ psumC, float* __restrict__ pssC) {
    __shared__ __align__(16) char pool[18432];   // Phi 8704 | Plo 8704 | red 1024
    char* Phi = pool;
    char* Plo = pool + 8704;
    float* redS = (float*)(pool + 17408);        // [4 waves][32]
    float* redQ = (float*)(pool + 17920);
    int t = threadIdx.x;
    int grp = blockIdx.x;                        // 1024 = b(4) x 256
    int b = grp >> 8, n0 = (grp & 255) * 4;
    int lane = t & 63, wv = t >> 6;
    int s0 = (wv >> 1) * 16, cb = (wv & 1) * 32;
    int l15 = lane & 15, lg = lane >> 4;

    // ---- zero halo rows (row 0 and 33 of each nl), swizzled ----
    if (t < 32) {
        int nl = t >> 3, rem = t & 7;
        int row = (rem >> 2) ? 33 : 0;
        int q = rem & 3;
        uint32_t off = (uint32_t)(nl * 2176 + row * 64 + q * 16);
        off ^= (uint32_t)((row & 7) << 4);
        *(uint4*)(Phi + off) = make_uint4(0u, 0u, 0u, 0u);
        *(uint4*)(Plo + off) = make_uint4(0u, 0u, 0u, 0u);
    }
    // ---- stage x -> bf16 hi/lo [nl][s+1][cin], swizzled (cin-pair packed) ----
#pragma unroll
    for (int it = 0; it < 2; it++) {
        int flat = it * 256 + t;                 // 512 = 16 cinp x 4 nl x 8 s4grp
        int cinp = flat & 15;
        int nl = (flat >> 4) & 3;
        int s4 = (flat >> 6) * 4;
        const float* xp = x + (((size_t)b * CIN + 2 * cinp) * NN + n0 + nl) * SS + s4;
        float4 u0 = *(const float4*)xp;
        float4 u1 = *(const float4*)(xp + NN * SS);
        float va[4] = {u0.x, u0.y, u0.z, u0.w};
        float vb[4] = {u1.x, u1.y, u1.z, u1.w};
#pragma unroll
        for (int j = 0; j < 4; j++) {
            uint32_t ha = f2b_rne(va[j]), hb = f2b_rne(vb[j]);
            uint32_t la = f2b_rne(va[j] - bfu(ha)), lb = f2b_rne(vb[j] - bfu(hb));
            int row = s4 + j + 1;
            uint32_t off = (uint32_t)(nl * 2176 + row * 64 + cinp * 4);
            off ^= (uint32_t)((row & 7) << 4);
            *(uint32_t*)(Phi + off) = ha | (hb << 16);
            *(uint32_t*)(Plo + off) = la | (lb << 16);
        }
    }
    // ---- weight fragments: coalesced prepacked loads ----
    bfrag Wh[2][3], Wl[2][3];
    {
        const uint4* WH = (const uint4*)wpk1H;
        const uint4* WL = (const uint4*)wpk1L;
        int cb2 = wv & 1;
#pragma unroll
        for (int ct = 0; ct < 2; ct++)
#pragma unroll
            for (int tap = 0; tap < 3; tap++) {
                int fi = ((cb2 * 2 + ct) * 3 + tap) * 64 + lane;
                uint4 H = WH[fi];
                uint4 L = WL[fi];
                Wh[ct][tap] = *(const bfrag*)&H;
                Wl[ct][tap] = *(const bfrag*)&L;
            }
    }
    __syncthreads();

    float bb0 = b1[cb + l15], bb1 = b1[cb + 16 + l15];
    float sS0 = 0.f, sS1 = 0.f, sQ0 = 0.f, sQ1 = 0.f;
    for (int nl = 0; nl < 4; nl++) {
        facc acc0 = {0.f, 0.f, 0.f, 0.f};
        facc acc1 = {0.f, 0.f, 0.f, 0.f};
#pragma unroll
        for (int tap = 0; tap < 3; tap++) {
            int row = s0 + tap + l15;            // a-frag: lane = row, k-grp = lg
            uint32_t off = (uint32_t)(nl * 2176 + row * 64 + (lg << 4));
            off ^= (uint32_t)((row & 7) << 4);
            bfrag ah = *(const bfrag*)(Phi + off);
            bfrag al = *(const bfrag*)(Plo + off);
            acc0 = __builtin_amdgcn_mfma_f32_16x16x32_bf16(ah, Wh[0][tap], acc0, 0, 0, 0);
            acc1 = __builtin_amdgcn_mfma_f32_16x16x32_bf16(ah, Wh[1][tap], acc1, 0, 0, 0);
            acc0 = __builtin_amdgcn_mfma_f32_16x16x32_bf16(al, Wh[0][tap], acc0, 0, 0, 0);
            acc1 = __builtin_amdgcn_mfma_f32_16x16x32_bf16(al, Wh[1][tap], acc1, 0, 0, 0);
            acc0 = __builtin_amdgcn_mfma_f32_16x16x32_bf16(ah, Wl[0][tap], acc0, 0, 0, 0);
            acc1 = __builtin_amdgcn_mfma_f32_16x16x32_bf16(ah, Wl[1][tap], acc1, 0, 0, 0);
        }
        // C/D layout: col=lane&15 (cout), row=(lane>>4)*4+reg (s, contiguous)
        int sx = s0 + (lg << 2);
        float* hp = h_pre + ((size_t)(b * NN + n0 + nl)) * (COUT * SS);
        {
            float y0 = acc0[0] + bb0, y1 = acc0[1] + bb0;
            float y2 = acc0[2] + bb0, y3 = acc0[3] + bb0;
            float4 o = {y0, y1, y2, y3};
            *(float4*)(hp + (cb + l15) * SS + sx) = o;
            sS0 += y0 + y1 + y2 + y3;
            sQ0 += y0 * y0 + y1 * y1 + y2 * y2 + y3 * y3;
        }
        {
            float y0 = acc1[0] + bb1, y1 = acc1[1] + bb1;
            float y2 = acc1[2] + bb1, y3 = acc1[3] + bb1;
            float4 o = {y0, y1, y2, y3};
            *(float4*)(hp + (cb + 16 + l15) * SS + sx) = o;
            sS1 += y0 + y1 + y2 + y3;
            sQ1 += y0 * y0 + y1 * y1 + y2 * y2 + y3 * y3;
        }
    }
    // lanes {l, l+16, l+32, l+48} share a cout -> shfl reduce
    sS0 += __shfl_down(sS0, 16); sS0 += __shfl_down(sS0, 32);
    sS1 += __shfl_down(sS1, 16); sS1 += __shfl_down(sS1, 32);
    sQ0 += __shfl_down(sQ0, 16); sQ0 += __shfl_down(sQ0, 32);
    sQ1 += __shfl_down(sQ1, 16); sQ1 += __shfl_down(sQ1, 32);
    if (lane < 16) {
        redS[wv * 32 + lane] = sS0;      redQ[wv * 32 + lane] = sQ0;
        redS[wv * 32 + 16 + lane] = sS1; redQ[wv * 32 + 16 + lane] = sQ1;
    }
    __syncthreads();
    if (t < 64) {                                // waves {wA, wA+2} share couts; c == t
        int wA = t >> 5, slot = t & 31;
        float S = redS[wA * 32 + slot] + redS[(wA + 2) * 32 + slot];
        float Q = redQ[wA * 32 + slot] + redQ[(wA + 2) * 32 + slot];
        psumC[(size_t)t * 1024 + grp] = S;
        pssC[(size_t)t * 1024 + grp] = Q;
    }
}

// ---------- reduce per-block partials -> scale/shift ----------
__global__ void bn_reduce_kernel(const float* __restrict__ psum, const float* __restrict__ pss,
                                 const float* __restrict__ g, const float* __restrict__ be,
                                 float* __restrict__ scale, float* __restrict__ shift,
                                 float invM, int stride, int nslots) {
    int c = blockIdx.x, t = threadIdx.x;    // 64 blocks x 256 threads
    const float* ps = psum + c * stride;
    const float* pq = pss + c * stride;
    float s = 0.f, q = 0.f;
    for (int i = t; i < nslots; i += 256) { s += ps[i]; q += pq[i]; }
#pragma unroll
    for (int o = 32; o > 0; o >>= 1) { s += __shfl_down(s, o); q += __shfl_down(q, o); }
    __shared__ float ws_[4], wq_[4];
    if ((t & 63) == 0) { ws_[t >> 6] = s; wq_[t >> 6] = q; }
    __syncthreads();
    if (t == 0) {
        float S = ws_[0] + ws_[1] + ws_[2] + ws_[3];
        float Q = wq_[0] + wq_[1] + wq_[2] + wq_[3];
        float m = S * invM, v = Q * invM - m * m;
        float sc = g[c] * rsqrtf(v + EPSV);
        scale[c] = sc;
        shift[c] = be[c] - m * sc;
    }
}

// ---------- bn1+ReLU + (h · Wg) via MFMA -> hw bf16 [B,N,S,C] ----------
__global__ __launch_bounds__(256, 2) void bn1_gemm_mfma_kernel(
    const float* __restrict__ h_pre, const float* __restrict__ scale1,
    const float* __restrict__ shift1, const uint32_t* __restrict__ wgpH,
    const uint32_t* __restrict__ wgpL, ushort* __restrict__ hw) {
    __shared__ __align__(16) char pool[32768];   // Xhi 16384 | Xlo 16384
    char* Xhi = pool;
    char* Xlo = pool + 16384;
    int t = threadIdx.x;
    int grp = blockIdx.x;                        // 1024 = b(4) x 256
    int b = grp >> 8, n0 = (grp & 255) * 4;
    int lane = t & 63, wv = t >> 6;
    int l15 = lane & 15, lg = lane >> 4;

    // ---- stage: BN1+ReLU, hi/lo split, c-pair packed u32 writes ----
#pragma unroll
    for (int it = 0; it < 4; it++) {
        int flat = it * 256 + t;                 // 1024 = cp(32) x nl(4) x sq(8)
        int sq = flat & 7;
        int nl = (flat >> 3) & 3;
        int cp = flat >> 5;
        int c = 2 * cp;
        int s4 = sq * 4;
        const float* p = h_pre + (((size_t)(b * NN + n0 + nl)) * COUT + c) * SS + s4;
        float4 u0 = *(const float4*)p;
        float4 u1 = *(const float4*)(p + SS);
        float scA = scale1[c], shA = shift1[c];
        float scB = scale1[c + 1], shB = shift1[c + 1];
        float va[4] = {fmaxf(u0.x * scA + shA, 0.f), fmaxf(u0.y * scA + shA, 0.f),
                       fmaxf(u0.z * scA + shA, 0.f), fmaxf(u0.w * scA + shA, 0.f)};
        float vb[4] = {fmaxf(u1.x * scB + shB, 0.f), fmaxf(u1.y * scB + shB, 0.f),
                       fmaxf(u1.z * scB + shB, 0.f), fmaxf(u1.w * scB + shB, 0.f)};
#pragma unroll
        for (int j = 0; j < 4; j++) {
            uint32_t ha = f2b_rne(va[j]), hb = f2b_rne(vb[j]);
            uint32_t la = f2b_rne(va[j] - bfu(ha)), lb = f2b_rne(vb[j] - bfu(hb));
            int row = nl * 32 + s4 + j;
            uint32_t off = (uint32_t)(row * 128 + 4 * cp);
            off ^= (uint32_t)((row & 7) << 4);
            *(uint32_t*)(Xhi + off) = ha | (hb << 16);
            *(uint32_t*)(Xlo + off) = la | (lb << 16);
        }
    }
    // ---- Wg fragments (A-operand): all 8 frags per wave, prepacked ----
    bfrag WgH[4][2], WgL[4][2];
    {
        const uint4* WH = (const uint4*)wgpH;
        const uint4* WL = (const uint4*)wgpL;
#pragma unroll
        for (int dt = 0; dt < 4; dt++)
#pragma unroll
            for (int kh = 0; kh < 2; kh++) {
                int fi = (dt * 2 + kh) * 64 + lane;
                uint4 H = WH[fi];
                uint4 L = WL[fi];
                WgH[dt][kh] = *(const bfrag*)&H;
                WgL[dt][kh] = *(const bfrag*)&L;
            }
    }
    __syncthreads();

    int n = n0 + wv;                             // wave = n
#pragma unroll
    for (int rt = 0; rt < 2; rt++) {             // s-half
        facc a0 = {0.f, 0.f, 0.f, 0.f};
        facc a1 = {0.f, 0.f, 0.f, 0.f};
        facc a2 = {0.f, 0.f, 0.f, 0.f};
        facc a3 = {0.f, 0.f, 0.f, 0.f};
#pragma unroll
        for (int kh = 0; kh < 2; kh++) {
            int row = wv * 32 + rt * 16 + l15;   // b-frag: col = row(n,s), k-grp = lg
            uint32_t off = (uint32_t)(row * 128 + kh * 64 + (lg << 4));
            off ^= (uint32_t)((row & 7) << 4);
            bfrag xh = *(const bfrag*)(Xhi + off);
            bfrag xl = *(const bfrag*)(Xlo + off);
            a0 = __builtin_amdgcn_mfma_f32_16x16x32_bf16(WgH[0][kh], xh, a0, 0, 0, 0);
            a1 = __builtin_amdgcn_mfma_f32_16x16x32_bf16(WgH[1][kh], xh, a1, 0, 0, 0);
            a2 = __builtin_amdgcn_mfma_f32_16x16x32_bf16(WgH[2][kh], xh, a2, 0, 0, 0);
            a3 = __builtin_amdgcn_mfma_f32_16x16x32_bf16(WgH[3][kh], xh, a3, 0, 0, 0);
            a0 = __builtin_amdgcn_mfma_f32_16x16x32_bf16(WgL[0][kh], xh, a0, 0, 0, 0);
            a1 = __builtin_amdgcn_mfma_f32_16x16x32_bf16(WgL[1][kh], xh, a1, 0, 0, 0);
            a2 = __builtin_amdgcn_mfma_f32_16x16x32_bf16(WgL[2][kh], xh, a2, 0, 0, 0);
            a3 = __builtin_amdgcn_mfma_f32_16x16x32_bf16(WgL[3][kh], xh, a3, 0, 0, 0);
            a0 = __builtin_amdgcn_mfma_f32_16x16x32_bf16(WgH[0][kh], xl, a0, 0, 0, 0);
            a1 = __builtin_amdgcn_mfma_f32_16x16x32_bf16(WgH[1][kh], xl, a1, 0, 0, 0);
            a2 = __builtin_amdgcn_mfma_f32_16x16x32_bf16(WgH[2][kh], xl, a2, 0, 0, 0);
            a3 = __builtin_amdgcn_mfma_f32_16x16x32_bf16(WgH[3][kh], xl, a3, 0, 0, 0);
        }
        // C/D: col = s-row = l15, row = d = dt*16 + lg*4 + reg
        int s = rt * 16 + l15;
        ushort* op = hw + (((size_t)(b * NN + n)) * SS + s) * CSP;
        {
            uint32_t p0 = f2b_rne(a0[0]) | (f2b_rne(a0[1]) << 16);
            uint32_t p1 = f2b_rne(a0[2]) | (f2b_rne(a0[3]) << 16);
            *(uint2*)(op + 0 * 16 + lg * 4) = make_uint2(p0, p1);
        }
        {
            uint32_t p0 = f2b_rne(a1[0]) | (f2b_rne(a1[1]) << 16);
            uint32_t p1 = f2b_rne(a1[2]) | (f2b_rne(a1[3]) << 16);
            *(uint2*)(op + 1 * 16 + lg * 4) = make_uint2(p0, p1);
        }
        {
            uint32_t p0 = f2b_rne(a2[0]) | (f2b_rne(a2[1]) << 16);
            uint32_t p1 = f2b_rne(a2[2]) | (f2b_rne(a2[3]) << 16);
            *(uint2*)(op + 2 * 16 + lg * 4) = make_uint2(p0, p1);
        }
        {
            uint32_t p0 = f2b_rne(a3[0]) | (f2b_rne(a3[1]) << 16);
            uint32_t p1 = f2b_rne(a3[2]) | (f2b_rne(a3[3]) << 16);
            *(uint2*)(op + 3 * 16 + lg * 4) = make_uint2(p0, p1);
        }
    }
}

// ---------- GCN aggregate v4: 2 nodes/block, 4-deep edge unroll ----------
// R8 accounting put gcn at ~60us vs ~10us traffic floor: latency/MLP-bound
// (2 dependent loads in flight x avg deg 16 x ~250cy L2 latency). v4: 4 edge
// rows in flight (2x MLP) + 2048 blocks (2x scheduler slack). psum2/pss2
// become [b][512grp][2048].
__global__ __launch_bounds__(256, 4) void gcn_kernel(
    const ushort* __restrict__ hw, const int* __restrict__ row_ptr,
    const int2* __restrict__ edata, const float* __restrict__ dinv,
    const float* __restrict__ bg, float* __restrict__ agg,
    float* __restrict__ psum2, float* __restrict__ pss2) {
    int t = threadIdx.x;
    int blk = blockIdx.x;                   // 2048
    int xcd = blk & 7, jj = blk >> 3;       // b-per-XCD-pair locality heuristic
    int b = xcd >> 1;
    int grp = (xcd & 1) + 2 * jj;           // 0..511
    int n0 = grp * 2;
    int off = t * 8;                        // ushort offset within 2048-elem row
    const ushort* hwb = hw + (size_t)b * NN * 2048;
    float bgv[8];
    int c0 = off & 63;
#pragma unroll
    for (int j = 0; j < 8; j++) bgv[j] = bg[c0 + j];
    float sS[8], sQ[8];
#pragma unroll
    for (int j = 0; j < 8; j++) { sS[j] = 0.f; sQ[j] = 0.f; }
    for (int g = 0; g < 2; g++) {
        int n = n0 + g;
        int r0 = row_ptr[n], r1 = row_ptr[n + 1];
        float dn = dinv[n];
        float acc[8];
        {   // self row, weight dn
            uint4 u = *(const uint4*)(hwb + (size_t)n * 2048 + off);
            acc[0] = dn * bfu(u.x); acc[1] = dn * bfh(u.x);
            acc[2] = dn * bfu(u.y); acc[3] = dn * bfh(u.y);
            acc[4] = dn * bfu(u.z); acc[5] = dn * bfh(u.z);
            acc[6] = dn * bfu(u.w); acc[7] = dn * bfh(u.w);
        }
        int r = r0;
        for (; r + 4 <= r1; r += 4) {       // 4 rows in flight
            int2 e0 = edata[r], e1 = edata[r + 1];
            int2 e2 = edata[r + 2], e3 = edata[r + 3];
            uint4 u0 = *(const uint4*)(hwb + (size_t)e0.x * 2048 + off);
            uint4 u1 = *(const uint4*)(hwb + (size_t)e1.x * 2048 + off);
            uint4 u2 = *(const uint4*)(hwb + (size_t)e2.x * 2048 + off);
            uint4 u3 = *(const uint4*)(hwb + (size_t)e3.x * 2048 + off);
            float w0 = __int_as_float(e0.y), w1 = __int_as_float(e1.y);
            float w2 = __int_as_float(e2.y), w3 = __int_as_float(e3.y);
            acc[0] += w0 * bfu(u0.x) + w1 * bfu(u1.x);
            acc[1] += w0 * bfh(u0.x) + w1 * bfh(u1.x);
            acc[2] += w0 * bfu(u0.y) + w1 * bfu(u1.y);
            acc[3] += w0 * bfh(u0.y) + w1 * bfh(u1.y);
            acc[4] += w0 * bfu(u0.z) + w1 * bfu(u1.z);
            acc[5] += w0 * bfh(u0.z) + w1 * bfh(u1.z);
            acc[6] += w0 * bfu(u0.w) + w1 * bfu(u1.w);
            acc[7] += w0 * bfh(u0.w) + w1 * bfh(u1.w);
            acc[0] += w2 * bfu(u2.x) + w3 * bfu(u3.x);
            acc[1] += w2 * bfh(u2.x) + w3 * bfh(u3.x);
            acc[2] += w2 * bfu(u2.y) + w3 * bfu(u3.y);
            acc[3] += w2 * bfh(u2.y) + w3 * bfh(u3.y);
            acc[4] += w2 * bfu(u2.z) + w3 * bfu(u3.z);
            acc[5] += w2 * bfh(u2.z) + w3 * bfh(u3.z);
            acc[6] += w2 * bfu(u2.w) + w3 * bfu(u3.w);
            acc[7] += w2 * bfh(u2.w) + w3 * bfh(u3.w);
        }
        for (; r < r1; r++) {
            int2 e = edata[r];
            uint4 u = *(const uint4*)(hwb + (size_t)e.x * 2048 + off);
            float w = __int_as_float(e.y);
            acc[0] += w * bfu(u.x); acc[1] += w * bfh(u.x);
            acc[2] += w * bfu(u.y); acc[3] += w * bfh(u.y);
            acc[4] += w * bfu(u.z); acc[5] += w * bfh(u.z);
            acc[6] += w * bfu(u.w); acc[7] += w * bfh(u.w);
        }
        float o[8];
#pragma unroll
        for (int j = 0; j < 8; j++) {
            o[j] = dn * acc[j] + bgv[j];
            sS[j] += o[j]; sQ[j] += o[j] * o[j];
        }
        float* ar = agg + ((size_t)(b * NN + n)) * 2048 + off;
        float4 o0 = {o[0], o[1], o[2], o[3]}, o1 = {o[4], o[5], o[6], o[7]};
        *(float4*)ar = o0; *(float4*)(ar + 4) = o1;
    }
    float* ps = psum2 + ((size_t)(b * 512 + grp)) * 2048 + off;
    float* pq = pss2 + ((size_t)(b * 512 + grp)) * 2048 + off;
    float4 s0v = {sS[0], sS[1], sS[2], sS[3]}, s1v = {sS[4], sS[5], sS[6], sS[7]};
    float4 q0v = {sQ[0], sQ[1], sQ[2], sQ[3]}, q1v = {sQ[4], sQ[5], sQ[6], sQ[7]};
    *(float4*)ps = s0v; *(float4*)(ps + 4) = s1v;
    *(float4*)pq = q0v; *(float4*)(pq + 4) = q1v;
}

// ---------- BN2 reduce v3: 256 blocks, 8 threads/(b,s,c), 512 groups ----------
__global__ __launch_bounds__(256) void bn2_reduce_kernel(
    const float* __restrict__ psum2, const float* __restrict__ pss2,
    const float* __restrict__ gs, const float* __restrict__ bes,
    float* __restrict__ scale2, float* __restrict__ shift2) {
    __shared__ float redS[4][32], redQ[4][32];
    int t = threadIdx.x;
    int slot = blockIdx.x * 32 + (t & 31);      // 256 blocks x 32 slots = 8192
    int b = slot >> 11, rem = slot & 2047;
    int chunk = t >> 5;                          // 0..7, 64 groups each
    const float* ps = psum2 + ((size_t)(b * 512 + chunk * 64)) * 2048 + rem;
    const float* pq = pss2 + ((size_t)(b * 512 + chunk * 64)) * 2048 + rem;
    float S = 0.f, Q = 0.f;
#pragma unroll 8
    for (int i = 0; i < 64; i++) {
        S += ps[(size_t)i * 2048];
        Q += pq[(size_t)i * 2048];
    }
    S += __shfl_down(S, 32);                     // chunk 2w+1 into 2w
    Q += __shfl_down(Q, 32);
    int w = t >> 6;
    if ((t & 63) < 32) { redS[w][t & 31] = S; redQ[w][t & 31] = Q; }
    __syncthreads();
    if (t < 32) {
        float Sf = redS[0][t] + redS[1][t] + redS[2][t] + redS[3][t];
        float Qf = redQ[0][t] + redQ[1][t] + redQ[2][t] + redQ[3][t];
        int slot0 = blockIdx.x * 32 + t;
        int d = slot0 & 63;
        float m = Sf * (1.f / NN);
        float v = Qf * (1.f / NN) - m * m;
        float sc = gs[d] * rsqrtf(v + EPSV);
        scale2[slot0] = sc;
        shift2[slot0] = bes[d] - m * sc;
    }
}

// ---------- conv2 via MFMA: BN2+ReLU -> hi/lo bf16 split -> 3-tap GEMM ----------
// Weights PREPACKED per-lane (w2pack).  (256,2) REQUIRED (R2 spill lesson).
// BN stats: non-atomic psumC/pssC slab (R4: atomics were a 44us L2-RMW drain).
__global__ __launch_bounds__(256, 2) void conv2_mfma_kernel(
    const float* __restrict__ agg, const float* __restrict__ scale2,
    const float* __restrict__ shift2, const uint32_t* __restrict__ wpkH,
    const uint32_t* __restrict__ wpkL,
    const float* __restrict__ b2, float* __restrict__ h2_pre,
    float* __restrict__ psumC, float* __restrict__ pssC) {
    __shared__ __align__(16) char pool[35840];     // 17408 hi | 17408 lo | 1024 red
    char* Phi = pool;
    char* Plo = pool + 17408;
    float* redS = (float*)(pool + 34816);          // [4 waves][32]
    float* redQ = (float*)(pool + 35328);
    int t = threadIdx.x;
    int grp = blockIdx.x;                          // 1024 = b(4) x 256
    int b = grp >> 8, n0 = (grp & 255) * 4;
    int lane = t & 63, wv = t >> 6;
    int s0 = (wv >> 1) * 16, cb = (wv & 1) * 32;
    int l15 = lane & 15, lg = lane >> 4;

    // ---- zero halo rows (t=0 and t=33 of each n-tile), swizzled ----
    if (t < 128) {
        int nl = t >> 5, rem = t & 31;
        int tr = (rem >> 4) ? 33 : 0;
        int j = rem & 15;
        uint32_t off = (uint32_t)(nl * 4352 + tr * 128 + 8 * j);
        off ^= (uint32_t)((tr & 7) << 4);
        *(uint2*)(Phi + off) = make_uint2(0u, 0u);
        *(uint2*)(Plo + off) = make_uint2(0u, 0u);
    }
    // ---- stage agg with BN2+ReLU, hi/lo bf16 split, swizzled write ----
#pragma unroll
    for (int i = 0; i < 8; i++) {
        int flat4 = i * 256 + t;                   // 2048 float4s = 4n x 32s x 16 cquads
        int c0 = 4 * (flat4 & 15);
        int s = (flat4 >> 4) & 31;
        int nl = flat4 >> 9;
        const float* p = agg + ((size_t)((b * NN + n0 + nl) * 32 + s)) * 64 + c0;
        float4 u = *(const float4*)p;
        int bsi = (b * 32 + s) * 64 + c0;
        float4 sc = *(const float4*)(scale2 + bsi);
        float4 sh = *(const float4*)(shift2 + bsi);
        float v0 = fmaxf(u.x * sc.x + sh.x, 0.f);
        float v1 = fmaxf(u.y * sc.y + sh.y, 0.f);
        float v2 = fmaxf(u.z * sc.z + sh.z, 0.f);
        float v3 = fmaxf(u.w * sc.w + sh.w, 0.f);
        uint32_t h0 = f2b_rne(v0), h1 = f2b_rne(v1), h2 = f2b_rne(v2), h3 = f2b_rne(v3);
        uint32_t l0 = f2b_rne(v0 - bfu(h0)), l1 = f2b_rne(v1 - bfu(h1));
        uint32_t l2 = f2b_rne(v2 - bfu(h2)), l3 = f2b_rne(v3 - bfu(h3));
        int tr = s + 1;
        uint32_t off = (uint32_t)(nl * 4352 + tr * 128 + 2 * c0);
        off ^= (uint32_t)((tr & 7) << 4);
        *(uint2*)(Phi + off) = make_uint2(h0 | (h1 << 16), h2 | (h3 << 16));
        *(uint2*)(Plo + off) = make_uint2(l0 | (l1 << 16), l2 | (l3 << 16));
    }

    // ---- weight fragments: coalesced prepacked loads (L2-resident, 1KB/wave) ----
    bfrag Wh[2][3][2], Wl[2][3][2];
    {
        const uint4* WH = (const uint4*)wpkH;
        const uint4* WL = (const uint4*)wpkL;
        int cb2 = wv & 1;
#pragma unroll
        for (int ct = 0; ct < 2; ct++)
#pragma unroll
            for (int tap = 0; tap < 3; tap++)
#pragma unroll
                for (int kh = 0; kh < 2; kh++) {
                    int fi = ((((cb2 * 2 + ct) * 3 + tap) * 2) + kh) * 64 + lane;
                    uint4 H = WH[fi];
                    uint4 L = WL[fi];
                    Wh[ct][tap][kh] = *(const bfrag*)&H;
                    Wl[ct][tap][kh] = *(const bfrag*)&L;
                }
    }
    __syncthreads();

    float bb0 = b2[cb + l15], bb1 = b2[cb + 16 + l15];
    float sS0 = 0.f, sS1 = 0.f, sQ0 = 0.f, sQ1 = 0.f;
    for (int nl = 0; nl < 4; nl++) {
        facc acc0 = {0.f, 0.f, 0.f, 0.f};
        facc acc1 = {0.f, 0.f, 0.f, 0.f};
#pragma unroll
        for (int tap = 0; tap < 3; tap++) {
#pragma unroll
            for (int kh = 0; kh < 2; kh++) {
                int row = s0 + tap + l15;          // a-frag: lane = row l&15, k-grp l>>4
                uint32_t off = (uint32_t)(nl * 4352 + row * 128 + kh * 64 + (lg << 4));
                off ^= (uint32_t)((row & 7) << 4);
                bfrag ah = *(const bfrag*)(Phi + off);
                bfrag al = *(const bfrag*)(Plo + off);
                acc0 = __builtin_amdgcn_mfma_f32_16x16x32_bf16(ah, Wh[0][tap][kh], acc0, 0, 0, 0);
                acc1 = __builtin_amdgcn_mfma_f32_16x16x32_bf16(ah, Wh[1][tap][kh], acc1, 0, 0, 0);
                acc0 = __builtin_amdgcn_mfma_f32_16x16x32_bf16(al, Wh[0][tap][kh], acc0, 0, 0, 0);
                acc1 = __builtin_amdgcn_mfma_f32_16x16x32_bf16(al, Wh[1][tap][kh], acc1, 0, 0, 0);
                acc0 = __builtin_amdgcn_mfma_f32_16x16x32_bf16(ah, Wl[0][tap][kh], acc0, 0, 0, 0);
                acc1 = __builtin_amdgcn_mfma_f32_16x16x32_bf16(ah, Wl[1][tap][kh], acc1, 0, 0, 0);
            }
        }
        // epilogue: C/D layout col=lane&15 (cout), row=(lane>>4)*4+reg (s, contiguous)
        int sx = s0 + (lg << 2);
        float* hp = h2_pre + ((size_t)(b * NN + n0 + nl)) * (COUT * SS);
        {
            float y0 = acc0[0] + bb0, y1 = acc0[1] + bb0;
            float y2 = acc0[2] + bb0, y3 = acc0[3] + bb0;
            float4 o = {y0, y1, y2, y3};
            *(float4*)(hp + (cb + l15) * SS + sx) = o;
            sS0 += y0 + y1 + y2 + y3;
            sQ0 += y0 * y0 + y1 * y1 + y2 * y2 + y3 * y3;
        }
        {
            float y0 = acc1[0] + bb1, y1 = acc1[1] + bb1;
            float y2 = acc1[2] + bb1, y3 = acc1[3] + bb1;
            float4 o = {y0, y1, y2, y3};
            *(float4*)(hp + (cb + 16 + l15) * SS + sx) = o;
            sS1 += y0 + y1 + y2 + y3;
            sQ1 += y0 * y0 + y1 * y1 + y2 * y2 + y3 * y3;
        }
    }
    // lanes {l, l+16, l+32, l+48} share a cout -> shfl reduce
    sS0 += __shfl_down(sS0, 16); sS0 += __shfl_down(sS0, 32);
    sS1 += __shfl_down(sS1, 16); sS1 += __shfl_down(sS1, 32);
    sQ0 += __shfl_down(sQ0, 16); sQ0 += __shfl_down(sQ0, 32);
    sQ1 += __shfl_down(sQ1, 16); sQ1 += __shfl_down(sQ1, 32);
    if (lane < 16) {
        redS[wv * 32 + lane] = sS0;      redQ[wv * 32 + lane] = sQ0;
        redS[wv * 32 + 16 + lane] = sS1; redQ[wv * 32 + 16 + lane] = sQ1;
    }
    __syncthreads();
    if (t < 64) {                                  // waves {wA, wA+2} share couts; c == t
        int wA = t >> 5, slot = t & 31;
        float S = redS[wA * 32 + slot] + redS[(wA + 2) * 32 + slot];
        float Q = redQ[wA * 32 + slot] + redQ[(wA + 2) * 32 + slot];
        psumC[(size_t)t * 1024 + grp] = S;         // [c][1024] slab, no RMW contention
        pssC[(size_t)t * 1024 + grp] = Q;
    }
}

// ---------- final: BN3+ReLU + residual 1x1 conv + ReLU, write [B,Cout,N,S] ----------
__global__ __launch_bounds__(256) void final_kernel(
    const float* __restrict__ x, const float* __restrict__ Wres,
    const float* __restrict__ bres, const float* __restrict__ h2_pre,
    const float* __restrict__ scale3, const float* __restrict__ shift3,
    float* __restrict__ out) {
    __shared__ __align__(16) float xs[CIN][36];
    __shared__ float wrl[COUT * 33];
    int t = threadIdx.x;
    int bn = blockIdx.x;
    int b = bn >> 10, n = bn & (NN - 1);
    {
        int sst = t & 31, cinb = t >> 5;            // bank 2-way
#pragma unroll
        for (int i = 0; i < 4; i++) {
            int cin = cinb + 8 * i;
            xs[cin][sst] = x[(((size_t)b * CIN + cin) * NN + n) * SS + sst];
        }
    }
#pragma unroll
    for (int i = 0; i < 2; i++) {
        int lin = (i * 256 + t) * 4;                // rows of 32
        int cw = lin >> 5, c0 = lin & 31;
        float4 v = *(const float4*)(Wres + lin);
        float* dst = &wrl[cw * 33 + c0];
        dst[0] = v.x; dst[1] = v.y; dst[2] = v.z; dst[3] = v.w;
    }
    __syncthreads();
    int cout = t >> 2, s0 = (t & 3) * 8;
    float res[8];
    float bb = bres[cout];
#pragma unroll
    for (int j = 0; j < 8; j++) res[j] = bb;
    const float* wrow = &wrl[cout * 33];
#pragma unroll 4
    for (int cin = 0; cin < CIN; cin++) {
        float w = wrow[cin];
        float4 xa = *(const float4*)&xs[cin][s0];
        float4 xb = *(const float4*)&xs[cin][s0 + 4];
        res[0] += xa.x * w; res[1] += xa.y * w; res[2] += xa.z * w; res[3] += xa.w * w;
        res[4] += xb.x * w; res[5] += xb.y * w; res[6] += xb.z * w; res[7] += xb.w * w;
    }
    const float* hp = h2_pre + (size_t)bn * COUT * SS + cout * SS + s0;
    float4 h0 = *(const float4*)hp, h1 = *(const float4*)(hp + 4);
    float h2[8] = {h0.x, h0.y, h0.z, h0.w, h1.x, h1.y, h1.z, h1.w};
    float sc = scale3[cout], sh = shift3[cout];
    float o[8];
#pragma unroll
    for (int j = 0; j < 8; j++) {
        float hv = fmaxf(sc * h2[j] + sh, 0.f);
        o[j] = fmaxf(hv + res[j], 0.f);
    }
    float* op = out + (((size_t)b * COUT + cout) * NN + n) * SS + s0;
    float4 o0 = {o[0], o[1], o[2], o[3]}, o1 = {o[4], o[5], o[6], o[7]};
    *(float4*)op = o0; *(float4*)(op + 4) = o1;
}

// ---------- host ----------
extern "C" void kernel_launch(void* const* d_in, const int* in_sizes, int n_in,
                              void* d_out, int out_size, void* d_ws, size_t ws_size,
                              hipStream_t stream) {
    const float* x    = (const float*)d_in[0];
    const int*   ei   = (const int*)  d_in[1];
    const float* W1   = (const float*)d_in[2];
    const float* b1   = (const float*)d_in[3];
    const float* g1   = (const float*)d_in[4];
    const float* be1  = (const float*)d_in[5];
    const float* Wg   = (const float*)d_in[6];
    const float* bg   = (const float*)d_in[7];
    const float* gs   = (const float*)d_in[8];
    const float* bes  = (const float*)d_in[9];
    const float* W2   = (const float*)d_in[10];
    const float* b2   = (const float*)d_in[11];
    const float* g2   = (const float*)d_in[12];
    const float* be2  = (const float*)d_in[13];
    const float* Wres = (const float*)d_in[14];
    const float* bres = (const float*)d_in[15];
    float* out = (float*)d_out;
    int E = in_sizes[1] / 2;

    char* ws = (char*)d_ws;
    // zeroed region: [0, 8192)
    int*   deg    = (int*)  (ws + 0);            // 4096 B
    int*   cursor = (int*)  (ws + 4096);         // 4096 B
    uint32_t* wpkH = (uint32_t*)(ws + 8192);     // 24576 B (packed W2 hi frags)
    uint32_t* wpkL = (uint32_t*)(ws + 32768);    // 24576 B -> 57344 (< 73728)
    int*   row_ptr= (int*)  (ws + 73728);        // 4100 B
    int*   flag   = (int*)  (ws + 77888);        // 4 B
    float* dinv   = (float*)(ws + 78080);        // 4096 B
    float* scale1 = (float*)(ws + 82176);        // 256 B each
    float* shift1 = (float*)(ws + 82432);
    float* scale3 = (float*)(ws + 82688);
    float* shift3 = (float*)(ws + 82944);
    float* scale2 = (float*)(ws + 83200);        // 32768 B
    float* shift2 = (float*)(ws + 115968);       // 32768 B -> 148736
    int2*  edata  = (int2*) (ws + 410880);       // 8*E = 131072 B -> 541952
    char*  bigA   = ws + 542720;                 // 33.55 MB region
    ushort* hwB   = (ushort*)bigA;
    float* h2p    = (float*)bigA;
    // BN-stat slabs + packed weight frags (beyond bigA's 33.55MB)
    float* psumC  = (float*)(ws + 34097152);     // 262144 B (64 ch x 1024 grp)
    float* pssC   = (float*)(ws + 34359296);     // 262144 B -> 34621440
    uint32_t* wpk1H = (uint32_t*)(ws + 34621440);// 12288 B (packed W1 hi frags)
    uint32_t* wpk1L = (uint32_t*)(ws + 34633728);// 12288 B -> 34646016
    uint32_t* wgpH  = (uint32_t*)(ws + 34646016);// 8192 B (packed Wg^T hi frags)
    uint32_t* wgpL  = (uint32_t*)(ws + 34654208);// 8192 B -> 34662400
    // gcn v4 512-group BN2 partial slabs (16.78 MB each; ws is 256 MiB)
    float* psum2  = (float*)(ws + 35651584);     // -> 52428800
    float* pss2   = (float*)(ws + 52428800);     // -> 69206016
    // d_out doubles as scratch: h_pre (conv1 out), then agg (gcn out).
    float* h_pre  = out;
    float* agg    = out;

    hipMemsetAsync(ws, 0, 8192, stream);
    w2pack_kernel<<<6, 256, 0, stream>>>(W2, wpkH, wpkL);
    w1pack_kernel<<<3, 256, 0, stream>>>(W1, wpk1H, wpk1L);
    wgpack_kernel<<<2, 256, 0, stream>>>(Wg, wgpH, wgpL);
    detect_kernel<<<1, 64, 0, stream>>>(ei, flag);
    int egrid = (E + 255) / 256;
    deg_count_kernel<<<egrid, 256, 0, stream>>>(ei, E, flag, deg);
    scan_kernel<<<1, NN, 0, stream>>>(deg, row_ptr, dinv);
    csr_fill_kernel<<<egrid, 256, 0, stream>>>(ei, E, flag, row_ptr, cursor, dinv, edata);

    conv1_mfma_kernel<<<1024, 256, 0, stream>>>(x, wpk1H, wpk1L, b1, h_pre, psumC, pssC);
    bn_reduce_kernel<<<64, 256, 0, stream>>>(psumC, pssC, g1, be1, scale1, shift1,
                                             1.f / (B_ * NN * SS), 1024, 1024);
    bn1_gemm_mfma_kernel<<<1024, 256, 0, stream>>>(h_pre, scale1, shift1, wgpH, wgpL, hwB);
    gcn_kernel<<<2048, 256, 0, stream>>>(hwB, row_ptr, edata, dinv, bg, agg, psum2, pss2);
    bn2_reduce_kernel<<<256, 256, 0, stream>>>(psum2, pss2, gs, bes, scale2, shift2);
    conv2_mfma_kernel<<<1024, 256, 0, stream>>>(agg, scale2, shift2, wpkH, wpkL,
                                                b2, h2p, psumC, pssC);
    bn_reduce_kernel<<<64, 256, 0, stream>>>(psumC, pssC, g2, be2, scale3, shift3,
                                             1.f / (B_ * NN * SS), 1024, 1024);
    final_kernel<<<B_ * NN, 256, 0, stream>>>(x, Wres, bres, h2p, scale3, shift3, out);
}

// Round 10
// 215.814 us; speedup vs baseline: 1.0495x; 1.0495x over previous
//
#include <hip/hip_runtime.h>
#include <stdint.h>

#define B_    4
#define CIN   32
#define NN    1024
#define SS    32
#define COUT  64
#define CSP   64
#define EPSV  1e-5f

typedef __attribute__((ext_vector_type(8))) short bfrag;   // 8 bf16 in 4 VGPRs
typedef __attribute__((ext_vector_type(4))) float facc;    // MFMA accumulator

__device__ __forceinline__ uint32_t f2b_rne(float f) {
    uint32_t x = __float_as_uint(f);
    return (x + 0x7fffu + ((x >> 16) & 1u)) >> 16;
}
__device__ __forceinline__ float bfu(uint32_t v) { return __uint_as_float(v << 16); }
__device__ __forceinline__ float bfh(uint32_t v) { return __uint_as_float(v & 0xffff0000u); }

// ---------- fused one-shot prep: W1/W2/Wg fragment packs + deg/cursor zero ----
// R10: was 4 separate launches (3 packs + memset) + detect kernel; each tiny.
// Dispatch-boundary overhead (~2us each) was the cost, not the work.
// blocks 0-5: W2 pack (24 frags x 64 lanes); 6-8: W1 (12 frags); 9-10: Wg (8);
// block 11: zero deg+cursor (2x4096B).
__global__ void pack_zero_kernel(const float* __restrict__ W1,
                                 const float* __restrict__ W2,
                                 const float* __restrict__ Wg,
                                 uint32_t* __restrict__ wpk1H, uint32_t* __restrict__ wpk1L,
                                 uint32_t* __restrict__ wpkH, uint32_t* __restrict__ wpkL,
                                 uint32_t* __restrict__ wgpH, uint32_t* __restrict__ wgpL,
                                 int* __restrict__ deg, int* __restrict__ cursor) {
    int blk = blockIdx.x, t = threadIdx.x;
    if (blk < 6) {                                   // ---- W2: B-operand frags ----
        int flat = blk * 256 + t;                    // 1536 = 24*64
        int lane = flat & 63, fi = flat >> 6;
        int kh = fi & 1, q = fi >> 1;
        int tap = q % 3, cc = q / 3;
        int ct = cc & 1, cb2 = cc >> 1;
        int cout = cb2 * 32 + ct * 16 + (lane & 15);
        int cbase = kh * 32 + (lane >> 4) * 8;
        const float* wp = W2 + ((size_t)cout * 64 + cbase) * 3 + tap;
        uint32_t h[8], l[8];
#pragma unroll
        for (int j = 0; j < 8; j++) {
            float w = wp[3 * j];
            uint32_t hb = f2b_rne(w);
            uint32_t lb = f2b_rne(w - bfu(hb));
            h[j] = hb; l[j] = lb;
        }
        uint4 H = {h[0] | (h[1] << 16), h[2] | (h[3] << 16),
                   h[4] | (h[5] << 16), h[6] | (h[7] << 16)};
        uint4 L = {l[0] | (l[1] << 16), l[2] | (l[3] << 16),
                   l[4] | (l[5] << 16), l[6] | (l[7] << 16)};
        ((uint4*)wpkH)[flat] = H;
        ((uint4*)wpkL)[flat] = L;
    } else if (blk < 9) {                            // ---- W1: B-operand frags ----
        int flat = (blk - 6) * 256 + t;              // 768 = 12*64
        int lane = flat & 63, fi = flat >> 6;
        int tap = fi % 3, cc = fi / 3;
        int ct = cc & 1, cb2 = cc >> 1;
        int cout = cb2 * 32 + ct * 16 + (lane & 15);
        int k0 = (lane >> 4) * 8;
        const float* wp = W1 + (size_t)cout * 96 + k0 * 3 + tap;  // W1[cout][cin][3]
        uint32_t h[8], l[8];
#pragma unroll
        for (int j = 0; j < 8; j++) {
            float w = wp[3 * j];
            uint32_t hb = f2b_rne(w);
            uint32_t lb = f2b_rne(w - bfu(hb));
            h[j] = hb; l[j] = lb;
        }
        uint4 H = {h[0] | (h[1] << 16), h[2] | (h[3] << 16),
                   h[4] | (h[5] << 16), h[6] | (h[7] << 16)};
        uint4 L = {l[0] | (l[1] << 16), l[2] | (l[3] << 16),
                   l[4] | (l[5] << 16), l[6] | (l[7] << 16)};
        ((uint4*)wpk1H)[flat] = H;
        ((uint4*)wpk1L)[flat] = L;
    } else if (blk < 11) {                           // ---- Wg^T: A-operand frags ----
        int flat = (blk - 9) * 256 + t;              // 512 = 8*64
        int lane = flat & 63, fi = flat >> 6;
        int kh = fi & 1, dt = fi >> 1;
        int d = dt * 16 + (lane & 15);
        int c0 = kh * 32 + (lane >> 4) * 8;
        const float* wp = Wg + (size_t)c0 * CSP + d;
        uint32_t h[8], l[8];
#pragma unroll
        for (int j = 0; j < 8; j++) {
            float w = wp[(size_t)j * CSP];
            uint32_t hb = f2b_rne(w);
            uint32_t lb = f2b_rne(w - bfu(hb));
            h[j] = hb; l[j] = lb;
        }
        uint4 H = {h[0] | (h[1] << 16), h[2] | (h[3] << 16),
                   h[4] | (h[5] << 16), h[6] | (h[7] << 16)};
        uint4 L = {l[0] | (l[1] << 16), l[2] | (l[3] << 16),
                   l[4] | (l[5] << 16), l[6] | (l[7] << 16)};
        ((uint4*)wgpH)[flat] = H;
        ((uint4*)wgpL)[flat] = L;
    } else {                                         // ---- zero deg + cursor ----
        int4 z = {0, 0, 0, 0};
        ((int4*)deg)[t] = z;                         // 256*16B = 4096
        ((int4*)cursor)[t] = z;
    }
}

// ---------- graph prep (int64-layout detect inlined per block, L2-hot) ----------
__global__ void deg_count_kernel(const int* __restrict__ ei, int E,
                                 int* __restrict__ deg) {
    __shared__ int snz;
    int t = threadIdx.x;
    if (t == 0) snz = 0;
    __syncthreads();
    if (t < 128 && ei[2 * t + 1] != 0) atomicOr(&snz, 1);
    __syncthreads();
    int i64 = (snz == 0) ? 1 : 0;                    // all-odd-words-zero => int64
    int e = blockIdx.x * 256 + t;
    if (e < E) {
        int d = i64 ? ei[2 * (E + e)] : ei[E + e];
        atomicAdd(&deg[d], 1);
    }
}

__global__ __launch_bounds__(1024) void scan_kernel(
    const int* __restrict__ deg, int* __restrict__ row_ptr, float* __restrict__ dinv) {
    __shared__ int sb[NN];
    int t = threadIdx.x;
    int v = deg[t];
    sb[t] = v;
    __syncthreads();
    for (int off = 1; off < NN; off <<= 1) {
        int tmp = (t >= off) ? sb[t - off] : 0;
        __syncthreads();
        sb[t] += tmp;
        __syncthreads();
    }
    row_ptr[t] = sb[t] - v;                 // exclusive scan
    if (t == NN - 1) row_ptr[NN] = sb[t];
    dinv[t] = rsqrtf((float)(v + 1));       // +1 self-loop
}

// Packed edge descriptors: {srcn, dinv[srcn]}
__global__ void csr_fill_kernel(const int* __restrict__ ei, int E,
                                const int* __restrict__ row_ptr, int* __restrict__ cursor,
                                const float* __restrict__ dinv, int2* __restrict__ edata) {
    __shared__ int snz;
    int t = threadIdx.x;
    if (t == 0) snz = 0;
    __syncthreads();
    if (t < 128 && ei[2 * t + 1] != 0) atomicOr(&snz, 1);
    __syncthreads();
    int i64 = (snz == 0) ? 1 : 0;
    int e = blockIdx.x * 256 + t;
    if (e < E) {
        int s = i64 ? ei[2 * e] : ei[e];
        int d = i64 ? ei[2 * (E + e)] : ei[E + e];
        int pos = atomicAdd(&cursor[d], 1);
        edata[row_ptr[d] + pos] = make_int2(s, __float_as_int(dinv[s]));
    }
}

// ---------- conv1 via MFMA: same recipe as conv2_mfma (R6 verified) ----------
__global__ __launch_bounds__(256, 2) void conv1_mfma_kernel(
    const float* __restrict__ x, const uint32_t* __restrict__ wpk1H,
    const uint32_t* __restrict__ wpk1L, const float* __restrict__ b1,
    float* __restrict__ h_pre, float* __restrict__ psumC, float* __restrict__ pssC) {
    __shared__ __align__(16) char pool[18432];   // Phi 8704 | Plo 8704 | red 1024
    char* Phi = pool;
    char* Plo = pool + 8704;
    float* redS = (float*)(pool + 17408);        // [4 waves][32]
    float* redQ = (float*)(pool + 17920);
    int t = threadIdx.x;
    int grp = blockIdx.x;                        // 1024 = b(4) x 256
    int b = grp >> 8, n0 = (grp & 255) * 4;
    int lane = t & 63, wv = t >> 6;
    int s0 = (wv >> 1) * 16, cb = (wv & 1) * 32;
    int l15 = lane & 15, lg = lane >> 4;

    // ---- zero halo rows (row 0 and 33 of each nl), swizzled ----
    if (t < 32) {
        int nl = t >> 3, rem = t & 7;
        int row = (rem >> 2) ? 33 : 0;
        int q = rem & 3;
        uint32_t off = (uint32_t)(nl * 2176 + row * 64 + q * 16);
        off ^= (uint32_t)((row & 7) << 4);
        *(uint4*)(Phi + off) = make_uint4(0u, 0u, 0u, 0u);
        *(uint4*)(Plo + off) = make_uint4(0u, 0u, 0u, 0u);
    }
    // ---- stage x -> bf16 hi/lo [nl][s+1][cin], swizzled (cin-pair packed) ----
#pragma unroll
    for (int it = 0; it < 2; it++) {
        int flat = it * 256 + t;                 // 512 = 16 cinp x 4 nl x 8 s4grp
        int cinp = flat & 15;
        int nl = (flat >> 4) & 3;
        int s4 = (flat >> 6) * 4;
        const float* xp = x + (((size_t)b * CIN + 2 * cinp) * NN + n0 + nl) * SS + s4;
        float4 u0 = *(const float4*)xp;
        float4 u1 = *(const float4*)(xp + NN * SS);
        float va[4] = {u0.x, u0.y, u0.z, u0.w};
        float vb[4] = {u1.x, u1.y, u1.z, u1.w};
#pragma unroll
        for (int j = 0; j < 4; j++) {
            uint32_t ha = f2b_rne(va[j]), hb = f2b_rne(vb[j]);
            uint32_t la = f2b_rne(va[j] - bfu(ha)), lb = f2b_rne(vb[j] - bfu(hb));
            int row = s4 + j + 1;
            uint32_t off = (uint32_t)(nl * 2176 + row * 64 + cinp * 4);
            off ^= (uint32_t)((row & 7) << 4);
            *(uint32_t*)(Phi + off) = ha | (hb << 16);
            *(uint32_t*)(Plo + off) = la | (lb << 16);
        }
    }
    // ---- weight fragments: coalesced prepacked loads ----
    bfrag Wh[2][3], Wl[2][3];
    {
        const uint4* WH = (const uint4*)wpk1H;
        const uint4* WL = (const uint4*)wpk1L;
        int cb2 = wv & 1;
#pragma unroll
        for (int ct = 0; ct < 2; ct++)
#pragma unroll
            for (int tap = 0; tap < 3; tap++) {
                int fi = ((cb2 * 2 + ct) * 3 + tap) * 64 + lane;
                uint4 H = WH[fi];
                uint4 L = WL[fi];
                Wh[ct][tap] = *(const bfrag*)&H;
                Wl[ct][tap] = *(const bfrag*)&L;
            }
    }
    __syncthreads();

    float bb0 = b1[cb + l15], bb1 = b1[cb + 16 + l15];
    float sS0 = 0.f, sS1 = 0.f, sQ0 = 0.f, sQ1 = 0.f;
    for (int nl = 0; nl < 4; nl++) {
        facc acc0 = {0.f, 0.f, 0.f, 0.f};
        facc acc1 = {0.f, 0.f, 0.f, 0.f};
#pragma unroll
        for (int tap = 0; tap < 3; tap++) {
            int row = s0 + tap + l15;            // a-frag: lane = row, k-grp = lg
            uint32_t off = (uint32_t)(nl * 2176 + row * 64 + (lg << 4));
            off ^= (uint32_t)((row & 7) << 4);
            bfrag ah = *(const bfrag*)(Phi + off);
            bfrag al = *(const bfrag*)(Plo + off);
            acc0 = __builtin_amdgcn_mfma_f32_16x16x32_bf16(ah, Wh[0][tap], acc0, 0, 0, 0);
            acc1 = __builtin_amdgcn_mfma_f32_16x16x32_bf16(ah, Wh[1][tap], acc1, 0, 0, 0);
            acc0 = __builtin_amdgcn_mfma_f32_16x16x32_bf16(al, Wh[0][tap], acc0, 0, 0, 0);
            acc1 = __builtin_amdgcn_mfma_f32_16x16x32_bf16(al, Wh[1][tap], acc1, 0, 0, 0);
            acc0 = __builtin_amdgcn_mfma_f32_16x16x32_bf16(ah, Wl[0][tap], acc0, 0, 0, 0);
            acc1 = __builtin_amdgcn_mfma_f32_16x16x32_bf16(ah, Wl[1][tap], acc1, 0, 0, 0);
        }
        // C/D layout: col=lane&15 (cout), row=(lane>>4)*4+reg (s, contiguous)
        int sx = s0 + (lg << 2);
        float* hp = h_pre + ((size_t)(b * NN + n0 + nl)) * (COUT * SS);
        {
            float y0 = acc0[0] + bb0, y1 = acc0[1] + bb0;
            float y2 = acc0[2] + bb0, y3 = acc0[3] + bb0;
            float4 o = {y0, y1, y2, y3};
            *(float4*)(hp + (cb + l15) * SS + sx) = o;
            sS0 += y0 + y1 + y2 + y3;
            sQ0 += y0 * y0 + y1 * y1 + y2 * y2 + y3 * y3;
        }
        {
            float y0 = acc1[0] + bb1, y1 = acc1[1] + bb1;
            float y2 = acc1[2] + bb1, y3 = acc1[3] + bb1;
            float4 o = {y0, y1, y2, y3};
            *(float4*)(hp + (cb + 16 + l15) * SS + sx) = o;
            sS1 += y0 + y1 + y2 + y3;
            sQ1 += y0 * y0 + y1 * y1 + y2 * y2 + y3 * y3;
        }
    }
    // lanes {l, l+16, l+32, l+48} share a cout -> shfl reduce
    sS0 += __shfl_down(sS0, 16); sS0 += __shfl_down(sS0, 32);
    sS1 += __shfl_down(sS1, 16); sS1 += __shfl_down(sS1, 32);
    sQ0 += __shfl_down(sQ0, 16); sQ0 += __shfl_down(sQ0, 32);
    sQ1 += __shfl_down(sQ1, 16); sQ1 += __shfl_down(sQ1, 32);
    if (lane < 16) {
        redS[wv * 32 + lane] = sS0;      redQ[wv * 32 + lane] = sQ0;
        redS[wv * 32 + 16 + lane] = sS1; redQ[wv * 32 + 16 + lane] = sQ1;
    }
    __syncthreads();
    if (t < 64) {                                // waves {wA, wA+2} share couts; c == t
        int wA = t >> 5, slot = t & 31;
        float S = redS[wA * 32 + slot] + redS[(wA + 2) * 32 + slot];
        float Q = redQ[wA * 32 + slot] + redQ[(wA + 2) * 32 + slot];
        psumC[(size_t)t * 1024 + grp] = S;
        pssC[(size_t)t * 1024 + grp] = Q;
    }
}

// ---------- reduce per-block partials -> scale/shift ----------
__global__ void bn_reduce_kernel(const float* __restrict__ psum, const float* __restrict__ pss,
                                 const float* __restrict__ g, const float* __restrict__ be,
                                 float* __restrict__ scale, float* __restrict__ shift,
                                 float invM, int stride, int nslots) {
    int c = blockIdx.x, t = threadIdx.x;    // 64 blocks x 256 threads
    const float* ps = psum + c * stride;
    const float* pq = pss + c * stride;
    float s = 0.f, q = 0.f;
    for (int i = t; i < nslots; i += 256) { s += ps[i]; q += pq[i]; }
#pragma unroll
    for (int o = 32; o > 0; o >>= 1) { s += __shfl_down(s, o); q += __shfl_down(q, o); }
    __shared__ float ws_[4], wq_[4];
    if ((t & 63) == 0) { ws_[t >> 6] = s; wq_[t >> 6] = q; }
    __syncthreads();
    if (t == 0) {
        float S = ws_[0] + ws_[1] + ws_[2] + ws_[3];
        float Q = wq_[0] + wq_[1] + wq_[2] + wq_[3];
        float m = S * invM, v = Q * invM - m * m;
        float sc = g[c] * rsqrtf(v + EPSV);
        scale[c] = sc;
        shift[c] = be[c] - m * sc;
    }
}

// ---------- bn1+ReLU + (h · Wg) via MFMA -> hw bf16 [B,N,S,C] ----------
__global__ __launch_bounds__(256, 2) void bn1_gemm_mfma_kernel(
    const float* __restrict__ h_pre, const float* __restrict__ scale1,
    const float* __restrict__ shift1, const uint32_t* __restrict__ wgpH,
    const uint32_t* __restrict__ wgpL, ushort* __restrict__ hw) {
    __shared__ __align__(16) char pool[32768];   // Xhi 16384 | Xlo 16384
    char* Xhi = pool;
    char* Xlo = pool + 16384;
    int t = threadIdx.x;
    int grp = blockIdx.x;                        // 1024 = b(4) x 256
    int b = grp >> 8, n0 = (grp & 255) * 4;
    int lane = t & 63, wv = t >> 6;
    int l15 = lane & 15, lg = lane >> 4;

    // ---- stage: BN1+ReLU, hi/lo split, c-pair packed u32 writes ----
#pragma unroll
    for (int it = 0; it < 4; it++) {
        int flat = it * 256 + t;                 // 1024 = cp(32) x nl(4) x sq(8)
        int sq = flat & 7;
        int nl = (flat >> 3) & 3;
        int cp = flat >> 5;
        int c = 2 * cp;
        int s4 = sq * 4;
        const float* p = h_pre + (((size_t)(b * NN + n0 + nl)) * COUT + c) * SS + s4;
        float4 u0 = *(const float4*)p;
        float4 u1 = *(const float4*)(p + SS);
        float scA = scale1[c], shA = shift1[c];
        float scB = scale1[c + 1], shB = shift1[c + 1];
        float va[4] = {fmaxf(u0.x * scA + shA, 0.f), fmaxf(u0.y * scA + shA, 0.f),
                       fmaxf(u0.z * scA + shA, 0.f), fmaxf(u0.w * scA + shA, 0.f)};
        float vb[4] = {fmaxf(u1.x * scB + shB, 0.f), fmaxf(u1.y * scB + shB, 0.f),
                       fmaxf(u1.z * scB + shB, 0.f), fmaxf(u1.w * scB + shB, 0.f)};
#pragma unroll
        for (int j = 0; j < 4; j++) {
            uint32_t ha = f2b_rne(va[j]), hb = f2b_rne(vb[j]);
            uint32_t la = f2b_rne(va[j] - bfu(ha)), lb = f2b_rne(vb[j] - bfu(hb));
            int row = nl * 32 + s4 + j;
            uint32_t off = (uint32_t)(row * 128 + 4 * cp);
            off ^= (uint32_t)((row & 7) << 4);
            *(uint32_t*)(Xhi + off) = ha | (hb << 16);
            *(uint32_t*)(Xlo + off) = la | (lb << 16);
        }
    }
    // ---- Wg fragments (A-operand): all 8 frags per wave, prepacked ----
    bfrag WgH[4][2], WgL[4][2];
    {
        const uint4* WH = (const uint4*)wgpH;
        const uint4* WL = (const uint4*)wgpL;
#pragma unroll
        for (int dt = 0; dt < 4; dt++)
#pragma unroll
            for (int kh = 0; kh < 2; kh++) {
                int fi = (dt * 2 + kh) * 64 + lane;
                uint4 H = WH[fi];
                uint4 L = WL[fi];
                WgH[dt][kh] = *(const bfrag*)&H;
                WgL[dt][kh] = *(const bfrag*)&L;
            }
    }
    __syncthreads();

    int n = n0 + wv;                             // wave = n
#pragma unroll
    for (int rt = 0; rt < 2; rt++) {             // s-half
        facc a0 = {0.f, 0.f, 0.f, 0.f};
        facc a1 = {0.f, 0.f, 0.f, 0.f};
        facc a2 = {0.f, 0.f, 0.f, 0.f};
        facc a3 = {0.f, 0.f, 0.f, 0.f};
#pragma unroll
        for (int kh = 0; kh < 2; kh++) {
            int row = wv * 32 + rt * 16 + l15;   // b-frag: col = row(n,s), k-grp = lg
            uint32_t off = (uint32_t)(row * 128 + kh * 64 + (lg << 4));
            off ^= (uint32_t)((row & 7) << 4);
            bfrag xh = *(const bfrag*)(Xhi + off);
            bfrag xl = *(const bfrag*)(Xlo + off);
            a0 = __builtin_amdgcn_mfma_f32_16x16x32_bf16(WgH[0][kh], xh, a0, 0, 0, 0);
            a1 = __builtin_amdgcn_mfma_f32_16x16x32_bf16(WgH[1][kh], xh, a1, 0, 0, 0);
            a2 = __builtin_amdgcn_mfma_f32_16x16x32_bf16(WgH[2][kh], xh, a2, 0, 0, 0);
            a3 = __builtin_amdgcn_mfma_f32_16x16x32_bf16(WgH[3][kh], xh, a3, 0, 0, 0);
            a0 = __builtin_amdgcn_mfma_f32_16x16x32_bf16(WgL[0][kh], xh, a0, 0, 0, 0);
            a1 = __builtin_amdgcn_mfma_f32_16x16x32_bf16(WgL[1][kh], xh, a1, 0, 0, 0);
            a2 = __builtin_amdgcn_mfma_f32_16x16x32_bf16(WgL[2][kh], xh, a2, 0, 0, 0);
            a3 = __builtin_amdgcn_mfma_f32_16x16x32_bf16(WgL[3][kh], xh, a3, 0, 0, 0);
            a0 = __builtin_amdgcn_mfma_f32_16x16x32_bf16(WgH[0][kh], xl, a0, 0, 0, 0);
            a1 = __builtin_amdgcn_mfma_f32_16x16x32_bf16(WgH[1][kh], xl, a1, 0, 0, 0);
            a2 = __builtin_amdgcn_mfma_f32_16x16x32_bf16(WgH[2][kh], xl, a2, 0, 0, 0);
            a3 = __builtin_amdgcn_mfma_f32_16x16x32_bf16(WgH[3][kh], xl, a3, 0, 0, 0);
        }
        // C/D: col = s-row = l15, row = d = dt*16 + lg*4 + reg
        int s = rt * 16 + l15;
        ushort* op = hw + (((size_t)(b * NN + n)) * SS + s) * CSP;
        {
            uint32_t p0 = f2b_rne(a0[0]) | (f2b_rne(a0[1]) << 16);
            uint32_t p1 = f2b_rne(a0[2]) | (f2b_rne(a0[3]) << 16);
            *(uint2*)(op + 0 * 16 + lg * 4) = make_uint2(p0, p1);
        }
        {
            uint32_t p0 = f2b_rne(a1[0]) | (f2b_rne(a1[1]) << 16);
            uint32_t p1 = f2b_rne(a1[2]) | (f2b_rne(a1[3]) << 16);
            *(uint2*)(op + 1 * 16 + lg * 4) = make_uint2(p0, p1);
        }
        {
            uint32_t p0 = f2b_rne(a2[0]) | (f2b_rne(a2[1]) << 16);
            uint32_t p1 = f2b_rne(a2[2]) | (f2b_rne(a2[3]) << 16);
            *(uint2*)(op + 2 * 16 + lg * 4) = make_uint2(p0, p1);
        }
        {
            uint32_t p0 = f2b_rne(a3[0]) | (f2b_rne(a3[1]) << 16);
            uint32_t p1 = f2b_rne(a3[2]) | (f2b_rne(a3[3]) << 16);
            *(uint2*)(op + 3 * 16 + lg * 4) = make_uint2(p0, p1);
        }
    }
}

// ---------- GCN aggregate v4: 2 nodes/block, 4-deep edge unroll ----------
__global__ __launch_bounds__(256, 4) void gcn_kernel(
    const ushort* __restrict__ hw, const int* __restrict__ row_ptr,
    const int2* __restrict__ edata, const float* __restrict__ dinv,
    const float* __restrict__ bg, float* __restrict__ agg,
    float* __restrict__ psum2, float* __restrict__ pss2) {
    int t = threadIdx.x;
    int blk = blockIdx.x;                   // 2048
    int xcd = blk & 7, jj = blk >> 3;       // b-per-XCD-pair locality heuristic
    int b = xcd >> 1;
    int grp = (xcd & 1) + 2 * jj;           // 0..511
    int n0 = grp * 2;
    int off = t * 8;                        // ushort offset within 2048-elem row
    const ushort* hwb = hw + (size_t)b * NN * 2048;
    float bgv[8];
    int c0 = off & 63;
#pragma unroll
    for (int j = 0; j < 8; j++) bgv[j] = bg[c0 + j];
    float sS[8], sQ[8];
#pragma unroll
    for (int j = 0; j < 8; j++) { sS[j] = 0.f; sQ[j] = 0.f; }
    for (int g = 0; g < 2; g++) {
        int n = n0 + g;
        int r0 = row_ptr[n], r1 = row_ptr[n + 1];
        float dn = dinv[n];
        float acc[8];
        {   // self row, weight dn
            uint4 u = *(const uint4*)(hwb + (size_t)n * 2048 + off);
            acc[0] = dn * bfu(u.x); acc[1] = dn * bfh(u.x);
            acc[2] = dn * bfu(u.y); acc[3] = dn * bfh(u.y);
            acc[4] = dn * bfu(u.z); acc[5] = dn * bfh(u.z);
            acc[6] = dn * bfu(u.w); acc[7] = dn * bfh(u.w);
        }
        int r = r0;
        for (; r + 4 <= r1; r += 4) {       // 4 rows in flight
            int2 e0 = edata[r], e1 = edata[r + 1];
            int2 e2 = edata[r + 2], e3 = edata[r + 3];
            uint4 u0 = *(const uint4*)(hwb + (size_t)e0.x * 2048 + off);
            uint4 u1 = *(const uint4*)(hwb + (size_t)e1.x * 2048 + off);
            uint4 u2 = *(const uint4*)(hwb + (size_t)e2.x * 2048 + off);
            uint4 u3 = *(const uint4*)(hwb + (size_t)e3.x * 2048 + off);
            float w0 = __int_as_float(e0.y), w1 = __int_as_float(e1.y);
            float w2 = __int_as_float(e2.y), w3 = __int_as_float(e3.y);
            acc[0] += w0 * bfu(u0.x) + w1 * bfu(u1.x);
            acc[1] += w0 * bfh(u0.x) + w1 * bfh(u1.x);
            acc[2] += w0 * bfu(u0.y) + w1 * bfu(u1.y);
            acc[3] += w0 * bfh(u0.y) + w1 * bfh(u1.y);
            acc[4] += w0 * bfu(u0.z) + w1 * bfu(u1.z);
            acc[5] += w0 * bfh(u0.z) + w1 * bfh(u1.z);
            acc[6] += w0 * bfu(u0.w) + w1 * bfu(u1.w);
            acc[7] += w0 * bfh(u0.w) + w1 * bfh(u1.w);
            acc[0] += w2 * bfu(u2.x) + w3 * bfu(u3.x);
            acc[1] += w2 * bfh(u2.x) + w3 * bfh(u3.x);
            acc[2] += w2 * bfu(u2.y) + w3 * bfu(u3.y);
            acc[3] += w2 * bfh(u2.y) + w3 * bfh(u3.y);
            acc[4] += w2 * bfu(u2.z) + w3 * bfu(u3.z);
            acc[5] += w2 * bfh(u2.z) + w3 * bfh(u3.z);
            acc[6] += w2 * bfu(u2.w) + w3 * bfu(u3.w);
            acc[7] += w2 * bfh(u2.w) + w3 * bfh(u3.w);
        }
        for (; r < r1; r++) {
            int2 e = edata[r];
            uint4 u = *(const uint4*)(hwb + (size_t)e.x * 2048 + off);
            float w = __int_as_float(e.y);
            acc[0] += w * bfu(u.x); acc[1] += w * bfh(u.x);
            acc[2] += w * bfu(u.y); acc[3] += w * bfh(u.y);
            acc[4] += w * bfu(u.z); acc[5] += w * bfh(u.z);
            acc[6] += w * bfu(u.w); acc[7] += w * bfh(u.w);
        }
        float o[8];
#pragma unroll
        for (int j = 0; j < 8; j++) {
            o[j] = dn * acc[j] + bgv[j];
            sS[j] += o[j]; sQ[j] += o[j] * o[j];
        }
        float* ar = agg + ((size_t)(b * NN + n)) * 2048 + off;
        float4 o0 = {o[0], o[1], o[2], o[3]}, o1 = {o[4], o[5], o[6], o[7]};
        *(float4*)ar = o0; *(float4*)(ar + 4) = o1;
    }
    float* ps = psum2 + ((size_t)(b * 512 + grp)) * 2048 + off;
    float* pq = pss2 + ((size_t)(b * 512 + grp)) * 2048 + off;
    float4 s0v = {sS[0], sS[1], sS[2], sS[3]}, s1v = {sS[4], sS[5], sS[6], sS[7]};
    float4 q0v = {sQ[0], sQ[1], sQ[2], sQ[3]}, q1v = {sQ[4], sQ[5], sQ[6], sQ[7]};
    *(float4*)ps = s0v; *(float4*)(ps + 4) = s1v;
    *(float4*)pq = q0v; *(float4*)(pq + 4) = q1v;
}

// ---------- BN2 reduce v3: 256 blocks, 8 threads/(b,s,c), 512 groups ----------
__global__ __launch_bounds__(256) void bn2_reduce_kernel(
    const float* __restrict__ psum2, const float* __restrict__ pss2,
    const float* __restrict__ gs, const float* __restrict__ bes,
    float* __restrict__ scale2, float* __restrict__ shift2) {
    __shared__ float redS[4][32], redQ[4][32];
    int t = threadIdx.x;
    int slot = blockIdx.x * 32 + (t & 31);      // 256 blocks x 32 slots = 8192
    int b = slot >> 11, rem = slot & 2047;
    int chunk = t >> 5;                          // 0..7, 64 groups each
    const float* ps = psum2 + ((size_t)(b * 512 + chunk * 64)) * 2048 + rem;
    const float* pq = pss2 + ((size_t)(b * 512 + chunk * 64)) * 2048 + rem;
    float S = 0.f, Q = 0.f;
#pragma unroll 8
    for (int i = 0; i < 64; i++) {
        S += ps[(size_t)i * 2048];
        Q += pq[(size_t)i * 2048];
    }
    S += __shfl_down(S, 32);                     // chunk 2w+1 into 2w
    Q += __shfl_down(Q, 32);
    int w = t >> 6;
    if ((t & 63) < 32) { redS[w][t & 31] = S; redQ[w][t & 31] = Q; }
    __syncthreads();
    if (t < 32) {
        float Sf = redS[0][t] + redS[1][t] + redS[2][t] + redS[3][t];
        float Qf = redQ[0][t] + redQ[1][t] + redQ[2][t] + redQ[3][t];
        int slot0 = blockIdx.x * 32 + t;
        int d = slot0 & 63;
        float m = Sf * (1.f / NN);
        float v = Qf * (1.f / NN) - m * m;
        float sc = gs[d] * rsqrtf(v + EPSV);
        scale2[slot0] = sc;
        shift2[slot0] = bes[d] - m * sc;
    }
}

// ---------- conv2 via MFMA: BN2+ReLU -> hi/lo bf16 split -> 3-tap GEMM ----------
// Weights PREPACKED per-lane (w2pack).  (256,2) REQUIRED (R2 spill lesson).
// BN stats: non-atomic psumC/pssC slab (R4: atomics were a 44us L2-RMW drain).
__global__ __launch_bounds__(256, 2) void conv2_mfma_kernel(
    const float* __restrict__ agg, const float* __restrict__ scale2,
    const float* __restrict__ shift2, const uint32_t* __restrict__ wpkH,
    const uint32_t* __restrict__ wpkL,
    const float* __restrict__ b2, float* __restrict__ h2_pre,
    float* __restrict__ psumC, float* __restrict__ pssC) {
    __shared__ __align__(16) char pool[35840];     // 17408 hi | 17408 lo | 1024 red
    char* Phi = pool;
    char* Plo = pool + 17408;
    float* redS = (float*)(pool + 34816);          // [4 waves][32]
    float* redQ = (float*)(pool + 35328);
    int t = threadIdx.x;
    int grp = blockIdx.x;                          // 1024 = b(4) x 256
    int b = grp >> 8, n0 = (grp & 255) * 4;
    int lane = t & 63, wv = t >> 6;
    int s0 = (wv >> 1) * 16, cb = (wv & 1) * 32;
    int l15 = lane & 15, lg = lane >> 4;

    // ---- zero halo rows (t=0 and t=33 of each n-tile), swizzled ----
    if (t < 128) {
        int nl = t >> 5, rem = t & 31;
        int tr = (rem >> 4) ? 33 : 0;
        int j = rem & 15;
        uint32_t off = (uint32_t)(nl * 4352 + tr * 128 + 8 * j);
        off ^= (uint32_t)((tr & 7) << 4);
        *(uint2*)(Phi + off) = make_uint2(0u, 0u);
        *(uint2*)(Plo + off) = make_uint2(0u, 0u);
    }
    // ---- stage agg with BN2+ReLU, hi/lo bf16 split, swizzled write ----
#pragma unroll
    for (int i = 0; i < 8; i++) {
        int flat4 = i * 256 + t;                   // 2048 float4s = 4n x 32s x 16 cquads
        int c0 = 4 * (flat4 & 15);
        int s = (flat4 >> 4) & 31;
        int nl = flat4 >> 9;
        const float* p = agg + ((size_t)((b * NN + n0 + nl) * 32 + s)) * 64 + c0;
        float4 u = *(const float4*)p;
        int bsi = (b * 32 + s) * 64 + c0;
        float4 sc = *(const float4*)(scale2 + bsi);
        float4 sh = *(const float4*)(shift2 + bsi);
        float v0 = fmaxf(u.x * sc.x + sh.x, 0.f);
        float v1 = fmaxf(u.y * sc.y + sh.y, 0.f);
        float v2 = fmaxf(u.z * sc.z + sh.z, 0.f);
        float v3 = fmaxf(u.w * sc.w + sh.w, 0.f);
        uint32_t h0 = f2b_rne(v0), h1 = f2b_rne(v1), h2 = f2b_rne(v2), h3 = f2b_rne(v3);
        uint32_t l0 = f2b_rne(v0 - bfu(h0)), l1 = f2b_rne(v1 - bfu(h1));
        uint32_t l2 = f2b_rne(v2 - bfu(h2)), l3 = f2b_rne(v3 - bfu(h3));
        int tr = s + 1;
        uint32_t off = (uint32_t)(nl * 4352 + tr * 128 + 2 * c0);
        off ^= (uint32_t)((tr & 7) << 4);
        *(uint2*)(Phi + off) = make_uint2(h0 | (h1 << 16), h2 | (h3 << 16));
        *(uint2*)(Plo + off) = make_uint2(l0 | (l1 << 16), l2 | (l3 << 16));
    }

    // ---- weight fragments: coalesced prepacked loads (L2-resident, 1KB/wave) ----
    bfrag Wh[2][3][2], Wl[2][3][2];
    {
        const uint4* WH = (const uint4*)wpkH;
        const uint4* WL = (const uint4*)wpkL;
        int cb2 = wv & 1;
#pragma unroll
        for (int ct = 0; ct < 2; ct++)
#pragma unroll
            for (int tap = 0; tap < 3; tap++)
#pragma unroll
                for (int kh = 0; kh < 2; kh++) {
                    int fi = ((((cb2 * 2 + ct) * 3 + tap) * 2) + kh) * 64 + lane;
                    uint4 H = WH[fi];
                    uint4 L = WL[fi];
                    Wh[ct][tap][kh] = *(const bfrag*)&H;
                    Wl[ct][tap][kh] = *(const bfrag*)&L;
                }
    }
    __syncthreads();

    float bb0 = b2[cb + l15], bb1 = b2[cb + 16 + l15];
    float sS0 = 0.f, sS1 = 0.f, sQ0 = 0.f, sQ1 = 0.f;
    for (int nl = 0; nl < 4; nl++) {
        facc acc0 = {0.f, 0.f, 0.f, 0.f};
        facc acc1 = {0.f, 0.f, 0.f, 0.f};
#pragma unroll
        for (int tap = 0; tap < 3; tap++) {
#pragma unroll
            for (int kh = 0; kh < 2; kh++) {
                int row = s0 + tap + l15;          // a-frag: lane = row l&15, k-grp l>>4
                uint32_t off = (uint32_t)(nl * 4352 + row * 128 + kh * 64 + (lg << 4));
                off ^= (uint32_t)((row & 7) << 4);
                bfrag ah = *(const bfrag*)(Phi + off);
                bfrag al = *(const bfrag*)(Plo + off);
                acc0 = __builtin_amdgcn_mfma_f32_16x16x32_bf16(ah, Wh[0][tap][kh], acc0, 0, 0, 0);
                acc1 = __builtin_amdgcn_mfma_f32_16x16x32_bf16(ah, Wh[1][tap][kh], acc1, 0, 0, 0);
                acc0 = __builtin_amdgcn_mfma_f32_16x16x32_bf16(al, Wh[0][tap][kh], acc0, 0, 0, 0);
                acc1 = __builtin_amdgcn_mfma_f32_16x16x32_bf16(al, Wh[1][tap][kh], acc1, 0, 0, 0);
                acc0 = __builtin_amdgcn_mfma_f32_16x16x32_bf16(ah, Wl[0][tap][kh], acc0, 0, 0, 0);
                acc1 = __builtin_amdgcn_mfma_f32_16x16x32_bf16(ah, Wl[1][tap][kh], acc1, 0, 0, 0);
            }
        }
        // epilogue: C/D layout col=lane&15 (cout), row=(lane>>4)*4+reg (s, contiguous)
        int sx = s0 + (lg << 2);
        float* hp = h2_pre + ((size_t)(b * NN + n0 + nl)) * (COUT * SS);
        {
            float y0 = acc0[0] + bb0, y1 = acc0[1] + bb0;
            float y2 = acc0[2] + bb0, y3 = acc0[3] + bb0;
            float4 o = {y0, y1, y2, y3};
            *(float4*)(hp + (cb + l15) * SS + sx) = o;
            sS0 += y0 + y1 + y2 + y3;
            sQ0 += y0 * y0 + y1 * y1 + y2 * y2 + y3 * y3;
        }
        {
            float y0 = acc1[0] + bb1, y1 = acc1[1] + bb1;
            float y2 = acc1[2] + bb1, y3 = acc1[3] + bb1;
            float4 o = {y0, y1, y2, y3};
            *(float4*)(hp + (cb + 16 + l15) * SS + sx) = o;
            sS1 += y0 + y1 + y2 + y3;
            sQ1 += y0 * y0 + y1 * y1 + y2 * y2 + y3 * y3;
        }
    }
    // lanes {l, l+16, l+32, l+48} share a cout -> shfl reduce
    sS0 += __shfl_down(sS0, 16); sS0 += __shfl_down(sS0, 32);
    sS1 += __shfl_down(sS1, 16); sS1 += __shfl_down(sS1, 32);
    sQ0 += __shfl_down(sQ0, 16); sQ0 += __shfl_down(sQ0, 32);
    sQ1 += __shfl_down(sQ1, 16); sQ1 += __shfl_down(sQ1, 32);
    if (lane < 16) {
        redS[wv * 32 + lane] = sS0;      redQ[wv * 32 + lane] = sQ0;
        redS[wv * 32 + 16 + lane] = sS1; redQ[wv * 32 + 16 + lane] = sQ1;
    }
    __syncthreads();
    if (t < 64) {                                  // waves {wA, wA+2} share couts; c == t
        int wA = t >> 5, slot = t & 31;
        float S = redS[wA * 32 + slot] + redS[(wA + 2) * 32 + slot];
        float Q = redQ[wA * 32 + slot] + redQ[(wA + 2) * 32 + slot];
        psumC[(size_t)t * 1024 + grp] = S;         // [c][1024] slab, no RMW contention
        pssC[(size_t)t * 1024 + grp] = Q;
    }
}

// ---------- final: BN3+ReLU + residual 1x1 conv + ReLU, write [B,Cout,N,S] ----------
__global__ __launch_bounds__(256) void final_kernel(
    const float* __restrict__ x, const float* __restrict__ Wres,
    const float* __restrict__ bres, const float* __restrict__ h2_pre,
    const float* __restrict__ scale3, const float* __restrict__ shift3,
    float* __restrict__ out) {
    __shared__ __align__(16) float xs[CIN][36];
    __shared__ float wrl[COUT * 33];
    int t = threadIdx.x;
    int bn = blockIdx.x;
    int b = bn >> 10, n = bn & (NN - 1);
    {
        int sst = t & 31, cinb = t >> 5;            // bank 2-way
#pragma unroll
        for (int i = 0; i < 4; i++) {
            int cin = cinb + 8 * i;
            xs[cin][sst] = x[(((size_t)b * CIN + cin) * NN + n) * SS + sst];
        }
    }
#pragma unroll
    for (int i = 0; i < 2; i++) {
        int lin = (i * 256 + t) * 4;                // rows of 32
        int cw = lin >> 5, c0 = lin & 31;
        float4 v = *(const float4*)(Wres + lin);
        float* dst = &wrl[cw * 33 + c0];
        dst[0] = v.x; dst[1] = v.y; dst[2] = v.z; dst[3] = v.w;
    }
    __syncthreads();
    int cout = t >> 2, s0 = (t & 3) * 8;
    float res[8];
    float bb = bres[cout];
#pragma unroll
    for (int j = 0; j < 8; j++) res[j] = bb;
    const float* wrow = &wrl[cout * 33];
#pragma unroll 4
    for (int cin = 0; cin < CIN; cin++) {
        float w = wrow[cin];
        float4 xa = *(const float4*)&xs[cin][s0];
        float4 xb = *(const float4*)&xs[cin][s0 + 4];
        res[0] += xa.x * w; res[1] += xa.y * w; res[2] += xa.z * w; res[3] += xa.w * w;
        res[4] += xb.x * w; res[5] += xb.y * w; res[6] += xb.z * w; res[7] += xb.w * w;
    }
    const float* hp = h2_pre + (size_t)bn * COUT * SS + cout * SS + s0;
    float4 h0 = *(const float4*)hp, h1 = *(const float4*)(hp + 4);
    float h2[8] = {h0.x, h0.y, h0.z, h0.w, h1.x, h1.y, h1.z, h1.w};
    float sc = scale3[cout], sh = shift3[cout];
    float o[8];
#pragma unroll
    for (int j = 0; j < 8; j++) {
        float hv = fmaxf(sc * h2[j] + sh, 0.f);
        o[j] = fmaxf(hv + res[j], 0.f);
    }
    float* op = out + (((size_t)b * COUT + cout) * NN + n) * SS + s0;
    float4 o0 = {o[0], o[1], o[2], o[3]}, o1 = {o[4], o[5], o[6], o[7]};
    *(float4*)op = o0; *(float4*)(op + 4) = o1;
}

// ---------- host ----------
extern "C" void kernel_launch(void* const* d_in, const int* in_sizes, int n_in,
                              void* d_out, int out_size, void* d_ws, size_t ws_size,
                              hipStream_t stream) {
    const float* x    = (const float*)d_in[0];
    const int*   ei   = (const int*)  d_in[1];
    const float* W1   = (const float*)d_in[2];
    const float* b1   = (const float*)d_in[3];
    const float* g1   = (const float*)d_in[4];
    const float* be1  = (const float*)d_in[5];
    const float* Wg   = (const float*)d_in[6];
    const float* bg   = (const float*)d_in[7];
    const float* gs   = (const float*)d_in[8];
    const float* bes  = (const float*)d_in[9];
    const float* W2   = (const float*)d_in[10];
    const float* b2   = (const float*)d_in[11];
    const float* g2   = (const float*)d_in[12];
    const float* be2  = (const float*)d_in[13];
    const float* Wres = (const float*)d_in[14];
    const float* bres = (const float*)d_in[15];
    float* out = (float*)d_out;
    int E = in_sizes[1] / 2;

    char* ws = (char*)d_ws;
    int*   deg    = (int*)  (ws + 0);            // 4096 B (zeroed by pack_zero)
    int*   cursor = (int*)  (ws + 4096);         // 4096 B (zeroed by pack_zero)
    uint32_t* wpkH = (uint32_t*)(ws + 8192);     // 24576 B (packed W2 hi frags)
    uint32_t* wpkL = (uint32_t*)(ws + 32768);    // 24576 B -> 57344 (< 73728)
    int*   row_ptr= (int*)  (ws + 73728);        // 4100 B
    float* dinv   = (float*)(ws + 78080);        // 4096 B
    float* scale1 = (float*)(ws + 82176);        // 256 B each
    float* shift1 = (float*)(ws + 82432);
    float* scale3 = (float*)(ws + 82688);
    float* shift3 = (float*)(ws + 82944);
    float* scale2 = (float*)(ws + 83200);        // 32768 B
    float* shift2 = (float*)(ws + 115968);       // 32768 B -> 148736
    int2*  edata  = (int2*) (ws + 410880);       // 8*E = 131072 B -> 541952
    char*  bigA   = ws + 542720;                 // 33.55 MB region
    ushort* hwB   = (ushort*)bigA;
    float* h2p    = (float*)bigA;
    // BN-stat slabs + packed weight frags (beyond bigA's 33.55MB)
    float* psumC  = (float*)(ws + 34097152);     // 262144 B (64 ch x 1024 grp)
    float* pssC   = (float*)(ws + 34359296);     // 262144 B -> 34621440
    uint32_t* wpk1H = (uint32_t*)(ws + 34621440);// 12288 B (packed W1 hi frags)
    uint32_t* wpk1L = (uint32_t*)(ws + 34633728);// 12288 B -> 34646016
    uint32_t* wgpH  = (uint32_t*)(ws + 34646016);// 8192 B (packed Wg^T hi frags)
    uint32_t* wgpL  = (uint32_t*)(ws + 34654208);// 8192 B -> 34662400
    // gcn v4 512-group BN2 partial slabs (16.78 MB each; ws is 256 MiB)
    float* psum2  = (float*)(ws + 35651584);     // -> 52428800
    float* pss2   = (float*)(ws + 52428800);     // -> 69206016
    // d_out doubles as scratch: h_pre (conv1 out), then agg (gcn out).
    float* h_pre  = out;
    float* agg    = out;

    pack_zero_kernel<<<12, 256, 0, stream>>>(W1, W2, Wg, wpk1H, wpk1L,
                                             wpkH, wpkL, wgpH, wgpL, deg, cursor);
    int egrid = (E + 255) / 256;
    deg_count_kernel<<<egrid, 256, 0, stream>>>(ei, E, deg);
    scan_kernel<<<1, NN, 0, stream>>>(deg, row_ptr, dinv);
    csr_fill_kernel<<<egrid, 256, 0, stream>>>(ei, E, row_ptr, cursor, dinv, edata);

    conv1_mfma_kernel<<<1024, 256, 0, stream>>>(x, wpk1H, wpk1L, b1, h_pre, psumC, pssC);
    bn_reduce_kernel<<<64, 256, 0, stream>>>(psumC, pssC, g1, be1, scale1, shift1,
                                             1.f / (B_ * NN * SS), 1024, 1024);
    bn1_gemm_mfma_kernel<<<1024, 256, 0, stream>>>(h_pre, scale1, shift1, wgpH, wgpL, hwB);
    gcn_kernel<<<2048, 256, 0, stream>>>(hwB, row_ptr, edata, dinv, bg, agg, psum2, pss2);
    bn2_reduce_kernel<<<256, 256, 0, stream>>>(psum2, pss2, gs, bes, scale2, shift2);
    conv2_mfma_kernel<<<1024, 256, 0, stream>>>(agg, scale2, shift2, wpkH, wpkL,
                                                b2, h2p, psumC, pssC);
    bn_reduce_kernel<<<64, 256, 0, stream>>>(psumC, pssC, g2, be2, scale3, shift3,
                                             1.f / (B_ * NN * SS), 1024, 1024);
    final_kernel<<<B_ * NN, 256, 0, stream>>>(x, Wres, bres, h2p, scale3, shift3, out);
}

// Round 11
// 205.713 us; speedup vs baseline: 1.1011x; 1.0491x over previous
//
#include <hip/hip_runtime.h>
#include <stdint.h>

#define B_    4
#define CIN   32
#define NN    1024
#define SS    32
#define COUT  64
#define CSP   64
#define EPSV  1e-5f

typedef __attribute__((ext_vector_type(8))) short bfrag;   // 8 bf16 in 4 VGPRs
typedef __attribute__((ext_vector_type(4))) float facc;    // MFMA accumulator

__device__ __forceinline__ uint32_t f2b_rne(float f) {
    uint32_t x = __float_as_uint(f);
    return (x + 0x7fffu + ((x >> 16) & 1u)) >> 16;
}
__device__ __forceinline__ float bfu(uint32_t v) { return __uint_as_float(v << 16); }
__device__ __forceinline__ float bfh(uint32_t v) { return __uint_as_float(v & 0xffff0000u); }

// ---------- fused one-shot prep: W1/W2/Wg fragment packs + deg/cursor zero ----
__global__ void pack_zero_kernel(const float* __restrict__ W1,
                                 const float* __restrict__ W2,
                                 const float* __restrict__ Wg,
                                 uint32_t* __restrict__ wpk1H, uint32_t* __restrict__ wpk1L,
                                 uint32_t* __restrict__ wpkH, uint32_t* __restrict__ wpkL,
                                 uint32_t* __restrict__ wgpH, uint32_t* __restrict__ wgpL,
                                 int* __restrict__ deg, int* __restrict__ cursor) {
    int blk = blockIdx.x, t = threadIdx.x;
    if (blk < 6) {                                   // ---- W2: B-operand frags ----
        int flat = blk * 256 + t;                    // 1536 = 24*64
        int lane = flat & 63, fi = flat >> 6;
        int kh = fi & 1, q = fi >> 1;
        int tap = q % 3, cc = q / 3;
        int ct = cc & 1, cb2 = cc >> 1;
        int cout = cb2 * 32 + ct * 16 + (lane & 15);
        int cbase = kh * 32 + (lane >> 4) * 8;
        const float* wp = W2 + ((size_t)cout * 64 + cbase) * 3 + tap;
        uint32_t h[8], l[8];
#pragma unroll
        for (int j = 0; j < 8; j++) {
            float w = wp[3 * j];
            uint32_t hb = f2b_rne(w);
            uint32_t lb = f2b_rne(w - bfu(hb));
            h[j] = hb; l[j] = lb;
        }
        uint4 H = {h[0] | (h[1] << 16), h[2] | (h[3] << 16),
                   h[4] | (h[5] << 16), h[6] | (h[7] << 16)};
        uint4 L = {l[0] | (l[1] << 16), l[2] | (l[3] << 16),
                   l[4] | (l[5] << 16), l[6] | (l[7] << 16)};
        ((uint4*)wpkH)[flat] = H;
        ((uint4*)wpkL)[flat] = L;
    } else if (blk < 9) {                            // ---- W1: B-operand frags ----
        int flat = (blk - 6) * 256 + t;              // 768 = 12*64
        int lane = flat & 63, fi = flat >> 6;
        int tap = fi % 3, cc = fi / 3;
        int ct = cc & 1, cb2 = cc >> 1;
        int cout = cb2 * 32 + ct * 16 + (lane & 15);
        int k0 = (lane >> 4) * 8;
        const float* wp = W1 + (size_t)cout * 96 + k0 * 3 + tap;  // W1[cout][cin][3]
        uint32_t h[8], l[8];
#pragma unroll
        for (int j = 0; j < 8; j++) {
            float w = wp[3 * j];
            uint32_t hb = f2b_rne(w);
            uint32_t lb = f2b_rne(w - bfu(hb));
            h[j] = hb; l[j] = lb;
        }
        uint4 H = {h[0] | (h[1] << 16), h[2] | (h[3] << 16),
                   h[4] | (h[5] << 16), h[6] | (h[7] << 16)};
        uint4 L = {l[0] | (l[1] << 16), l[2] | (l[3] << 16),
                   l[4] | (l[5] << 16), l[6] | (l[7] << 16)};
        ((uint4*)wpk1H)[flat] = H;
        ((uint4*)wpk1L)[flat] = L;
    } else if (blk < 11) {                           // ---- Wg^T: A-operand frags ----
        int flat = (blk - 9) * 256 + t;              // 512 = 8*64
        int lane = flat & 63, fi = flat >> 6;
        int kh = fi & 1, dt = fi >> 1;
        int d = dt * 16 + (lane & 15);
        int c0 = kh * 32 + (lane >> 4) * 8;
        const float* wp = Wg + (size_t)c0 * CSP + d;
        uint32_t h[8], l[8];
#pragma unroll
        for (int j = 0; j < 8; j++) {
            float w = wp[(size_t)j * CSP];
            uint32_t hb = f2b_rne(w);
            uint32_t lb = f2b_rne(w - bfu(hb));
            h[j] = hb; l[j] = lb;
        }
        uint4 H = {h[0] | (h[1] << 16), h[2] | (h[3] << 16),
                   h[4] | (h[5] << 16), h[6] | (h[7] << 16)};
        uint4 L = {l[0] | (l[1] << 16), l[2] | (l[3] << 16),
                   l[4] | (l[5] << 16), l[6] | (l[7] << 16)};
        ((uint4*)wgpH)[flat] = H;
        ((uint4*)wgpL)[flat] = L;
    } else {                                         // ---- zero deg + cursor ----
        int4 z = {0, 0, 0, 0};
        ((int4*)deg)[t] = z;                         // 256*16B = 4096
        ((int4*)cursor)[t] = z;
    }
}

// ---------- graph prep (int64-layout detect inlined per block, L2-hot) ----------
__global__ void deg_count_kernel(const int* __restrict__ ei, int E,
                                 int* __restrict__ deg) {
    __shared__ int snz;
    int t = threadIdx.x;
    if (t == 0) snz = 0;
    __syncthreads();
    if (t < 128 && ei[2 * t + 1] != 0) atomicOr(&snz, 1);
    __syncthreads();
    int i64 = (snz == 0) ? 1 : 0;                    // all-odd-words-zero => int64
    int e = blockIdx.x * 256 + t;
    if (e < E) {
        int d = i64 ? ei[2 * (E + e)] : ei[E + e];
        atomicAdd(&deg[d], 1);
    }
}

__global__ __launch_bounds__(1024) void scan_kernel(
    const int* __restrict__ deg, int* __restrict__ row_ptr, float* __restrict__ dinv) {
    __shared__ int sb[NN];
    int t = threadIdx.x;
    int v = deg[t];
    sb[t] = v;
    __syncthreads();
    for (int off = 1; off < NN; off <<= 1) {
        int tmp = (t >= off) ? sb[t - off] : 0;
        __syncthreads();
        sb[t] += tmp;
        __syncthreads();
    }
    row_ptr[t] = sb[t] - v;                 // exclusive scan
    if (t == NN - 1) row_ptr[NN] = sb[t];
    dinv[t] = rsqrtf((float)(v + 1));       // +1 self-loop
}

// Packed edge descriptors: {srcn, dinv[srcn]}
__global__ void csr_fill_kernel(const int* __restrict__ ei, int E,
                                const int* __restrict__ row_ptr, int* __restrict__ cursor,
                                const float* __restrict__ dinv, int2* __restrict__ edata) {
    __shared__ int snz;
    int t = threadIdx.x;
    if (t == 0) snz = 0;
    __syncthreads();
    if (t < 128 && ei[2 * t + 1] != 0) atomicOr(&snz, 1);
    __syncthreads();
    int i64 = (snz == 0) ? 1 : 0;
    int e = blockIdx.x * 256 + t;
    if (e < E) {
        int s = i64 ? ei[2 * e] : ei[e];
        int d = i64 ? ei[2 * (E + e)] : ei[E + e];
        int pos = atomicAdd(&cursor[d], 1);
        edata[row_ptr[d] + pos] = make_int2(s, __float_as_int(dinv[s]));
    }
}

// ---------- conv1 via MFMA: same recipe as conv2_mfma (R6 verified) ----------
__global__ __launch_bounds__(256, 2) void conv1_mfma_kernel(
    const float* __restrict__ x, const uint32_t* __restrict__ wpk1H,
    const uint32_t* __restrict__ wpk1L, const float* __restrict__ b1,
    float* __restrict__ h_pre, float* __restrict__ psumC, float* __restrict__ pssC) {
    __shared__ __align__(16) char pool[18432];   // Phi 8704 | Plo 8704 | red 1024
    char* Phi = pool;
    char* Plo = pool + 8704;
    float* redS = (float*)(pool + 17408);        // [4 waves][32]
    float* redQ = (float*)(pool + 17920);
    int t = threadIdx.x;
    int grp = blockIdx.x;                        // 1024 = b(4) x 256
    int b = grp >> 8, n0 = (grp & 255) * 4;
    int lane = t & 63, wv = t >> 6;
    int s0 = (wv >> 1) * 16, cb = (wv & 1) * 32;
    int l15 = lane & 15, lg = lane >> 4;

    // ---- zero halo rows (row 0 and 33 of each nl), swizzled ----
    if (t < 32) {
        int nl = t >> 3, rem = t & 7;
        int row = (rem >> 2) ? 33 : 0;
        int q = rem & 3;
        uint32_t off = (uint32_t)(nl * 2176 + row * 64 + q * 16);
        off ^= (uint32_t)((row & 7) << 4);
        *(uint4*)(Phi + off) = make_uint4(0u, 0u, 0u, 0u);
        *(uint4*)(Plo + off) = make_uint4(0u, 0u, 0u, 0u);
    }
    // ---- stage x -> bf16 hi/lo [nl][s+1][cin], swizzled (cin-pair packed) ----
#pragma unroll
    for (int it = 0; it < 2; it++) {
        int flat = it * 256 + t;                 // 512 = 16 cinp x 4 nl x 8 s4grp
        int cinp = flat & 15;
        int nl = (flat >> 4) & 3;
        int s4 = (flat >> 6) * 4;
        const float* xp = x + (((size_t)b * CIN + 2 * cinp) * NN + n0 + nl) * SS + s4;
        float4 u0 = *(const float4*)xp;
        float4 u1 = *(const float4*)(xp + NN * SS);
        float va[4] = {u0.x, u0.y, u0.z, u0.w};
        float vb[4] = {u1.x, u1.y, u1.z, u1.w};
#pragma unroll
        for (int j = 0; j < 4; j++) {
            uint32_t ha = f2b_rne(va[j]), hb = f2b_rne(vb[j]);
            uint32_t la = f2b_rne(va[j] - bfu(ha)), lb = f2b_rne(vb[j] - bfu(hb));
            int row = s4 + j + 1;
            uint32_t off = (uint32_t)(nl * 2176 + row * 64 + cinp * 4);
            off ^= (uint32_t)((row & 7) << 4);
            *(uint32_t*)(Phi + off) = ha | (hb << 16);
            *(uint32_t*)(Plo + off) = la | (lb << 16);
        }
    }
    // ---- weight fragments: coalesced prepacked loads ----
    bfrag Wh[2][3], Wl[2][3];
    {
        const uint4* WH = (const uint4*)wpk1H;
        const uint4* WL = (const uint4*)wpk1L;
        int cb2 = wv & 1;
#pragma unroll
        for (int ct = 0; ct < 2; ct++)
#pragma unroll
            for (int tap = 0; tap < 3; tap++) {
                int fi = ((cb2 * 2 + ct) * 3 + tap) * 64 + lane;
                uint4 H = WH[fi];
                uint4 L = WL[fi];
                Wh[ct][tap] = *(const bfrag*)&H;
                Wl[ct][tap] = *(const bfrag*)&L;
            }
    }
    __syncthreads();

    float bb0 = b1[cb + l15], bb1 = b1[cb + 16 + l15];
    float sS0 = 0.f, sS1 = 0.f, sQ0 = 0.f, sQ1 = 0.f;
    for (int nl = 0; nl < 4; nl++) {
        facc acc0 = {0.f, 0.f, 0.f, 0.f};
        facc acc1 = {0.f, 0.f, 0.f, 0.f};
#pragma unroll
        for (int tap = 0; tap < 3; tap++) {
            int row = s0 + tap + l15;            // a-frag: lane = row, k-grp = lg
            uint32_t off = (uint32_t)(nl * 2176 + row * 64 + (lg << 4));
            off ^= (uint32_t)((row & 7) << 4);
            bfrag ah = *(const bfrag*)(Phi + off);
            bfrag al = *(const bfrag*)(Plo + off);
            acc0 = __builtin_amdgcn_mfma_f32_16x16x32_bf16(ah, Wh[0][tap], acc0, 0, 0, 0);
            acc1 = __builtin_amdgcn_mfma_f32_16x16x32_bf16(ah, Wh[1][tap], acc1, 0, 0, 0);
            acc0 = __builtin_amdgcn_mfma_f32_16x16x32_bf16(al, Wh[0][tap], acc0, 0, 0, 0);
            acc1 = __builtin_amdgcn_mfma_f32_16x16x32_bf16(al, Wh[1][tap], acc1, 0, 0, 0);
            acc0 = __builtin_amdgcn_mfma_f32_16x16x32_bf16(ah, Wl[0][tap], acc0, 0, 0, 0);
            acc1 = __builtin_amdgcn_mfma_f32_16x16x32_bf16(ah, Wl[1][tap], acc1, 0, 0, 0);
        }
        // C/D layout: col=lane&15 (cout), row=(lane>>4)*4+reg (s, contiguous)
        int sx = s0 + (lg << 2);
        float* hp = h_pre + ((size_t)(b * NN + n0 + nl)) * (COUT * SS);
        {
            float y0 = acc0[0] + bb0, y1 = acc0[1] + bb0;
            float y2 = acc0[2] + bb0, y3 = acc0[3] + bb0;
            float4 o = {y0, y1, y2, y3};
            *(float4*)(hp + (cb + l15) * SS + sx) = o;
            sS0 += y0 + y1 + y2 + y3;
            sQ0 += y0 * y0 + y1 * y1 + y2 * y2 + y3 * y3;
        }
        {
            float y0 = acc1[0] + bb1, y1 = acc1[1] + bb1;
            float y2 = acc1[2] + bb1, y3 = acc1[3] + bb1;
            float4 o = {y0, y1, y2, y3};
            *(float4*)(hp + (cb + 16 + l15) * SS + sx) = o;
            sS1 += y0 + y1 + y2 + y3;
            sQ1 += y0 * y0 + y1 * y1 + y2 * y2 + y3 * y3;
        }
    }
    // lanes {l, l+16, l+32, l+48} share a cout -> shfl reduce
    sS0 += __shfl_down(sS0, 16); sS0 += __shfl_down(sS0, 32);
    sS1 += __shfl_down(sS1, 16); sS1 += __shfl_down(sS1, 32);
    sQ0 += __shfl_down(sQ0, 16); sQ0 += __shfl_down(sQ0, 32);
    sQ1 += __shfl_down(sQ1, 16); sQ1 += __shfl_down(sQ1, 32);
    if (lane < 16) {
        redS[wv * 32 + lane] = sS0;      redQ[wv * 32 + lane] = sQ0;
        redS[wv * 32 + 16 + lane] = sS1; redQ[wv * 32 + 16 + lane] = sQ1;
    }
    __syncthreads();
    if (t < 64) {                                // waves {wA, wA+2} share couts; c == t
        int wA = t >> 5, slot = t & 31;
        float S = redS[wA * 32 + slot] + redS[(wA + 2) * 32 + slot];
        float Q = redQ[wA * 32 + slot] + redQ[(wA + 2) * 32 + slot];
        psumC[(size_t)t * 1024 + grp] = S;
        pssC[(size_t)t * 1024 + grp] = Q;
    }
}

// ---------- reduce per-block partials -> scale/shift ----------
__global__ void bn_reduce_kernel(const float* __restrict__ psum, const float* __restrict__ pss,
                                 const float* __restrict__ g, const float* __restrict__ be,
                                 float* __restrict__ scale, float* __restrict__ shift,
                                 float invM, int stride, int nslots) {
    int c = blockIdx.x, t = threadIdx.x;    // 64 blocks x 256 threads
    const float* ps = psum + c * stride;
    const float* pq = pss + c * stride;
    float s = 0.f, q = 0.f;
    for (int i = t; i < nslots; i += 256) { s += ps[i]; q += pq[i]; }
#pragma unroll
    for (int o = 32; o > 0; o >>= 1) { s += __shfl_down(s, o); q += __shfl_down(q, o); }
    __shared__ float ws_[4], wq_[4];
    if ((t & 63) == 0) { ws_[t >> 6] = s; wq_[t >> 6] = q; }
    __syncthreads();
    if (t == 0) {
        float S = ws_[0] + ws_[1] + ws_[2] + ws_[3];
        float Q = wq_[0] + wq_[1] + wq_[2] + wq_[3];
        float m = S * invM, v = Q * invM - m * m;
        float sc = g[c] * rsqrtf(v + EPSV);
        scale[c] = sc;
        shift[c] = be[c] - m * sc;
    }
}

// ---------- bn1+ReLU + (h · Wg) via MFMA -> hw bf16 [B,N,S,C] ----------
__global__ __launch_bounds__(256, 2) void bn1_gemm_mfma_kernel(
    const float* __restrict__ h_pre, const float* __restrict__ scale1,
    const float* __restrict__ shift1, const uint32_t* __restrict__ wgpH,
    const uint32_t* __restrict__ wgpL, ushort* __restrict__ hw) {
    __shared__ __align__(16) char pool[32768];   // Xhi 16384 | Xlo 16384
    char* Xhi = pool;
    char* Xlo = pool + 16384;
    int t = threadIdx.x;
    int grp = blockIdx.x;                        // 1024 = b(4) x 256
    int b = grp >> 8, n0 = (grp & 255) * 4;
    int lane = t & 63, wv = t >> 6;
    int l15 = lane & 15, lg = lane >> 4;

    // ---- stage: BN1+ReLU, hi/lo split, c-pair packed u32 writes ----
#pragma unroll
    for (int it = 0; it < 4; it++) {
        int flat = it * 256 + t;                 // 1024 = cp(32) x nl(4) x sq(8)
        int sq = flat & 7;
        int nl = (flat >> 3) & 3;
        int cp = flat >> 5;
        int c = 2 * cp;
        int s4 = sq * 4;
        const float* p = h_pre + (((size_t)(b * NN + n0 + nl)) * COUT + c) * SS + s4;
        float4 u0 = *(const float4*)p;
        float4 u1 = *(const float4*)(p + SS);
        float scA = scale1[c], shA = shift1[c];
        float scB = scale1[c + 1], shB = shift1[c + 1];
        float va[4] = {fmaxf(u0.x * scA + shA, 0.f), fmaxf(u0.y * scA + shA, 0.f),
                       fmaxf(u0.z * scA + shA, 0.f), fmaxf(u0.w * scA + shA, 0.f)};
        float vb[4] = {fmaxf(u1.x * scB + shB, 0.f), fmaxf(u1.y * scB + shB, 0.f),
                       fmaxf(u1.z * scB + shB, 0.f), fmaxf(u1.w * scB + shB, 0.f)};
#pragma unroll
        for (int j = 0; j < 4; j++) {
            uint32_t ha = f2b_rne(va[j]), hb = f2b_rne(vb[j]);
            uint32_t la = f2b_rne(va[j] - bfu(ha)), lb = f2b_rne(vb[j] - bfu(hb));
            int row = nl * 32 + s4 + j;
            uint32_t off = (uint32_t)(row * 128 + 4 * cp);
            off ^= (uint32_t)((row & 7) << 4);
            *(uint32_t*)(Xhi + off) = ha | (hb << 16);
            *(uint32_t*)(Xlo + off) = la | (lb << 16);
        }
    }
    // ---- Wg fragments (A-operand): all 8 frags per wave, prepacked ----
    bfrag WgH[4][2], WgL[4][2];
    {
        const uint4* WH = (const uint4*)wgpH;
        const uint4* WL = (const uint4*)wgpL;
#pragma unroll
        for (int dt = 0; dt < 4; dt++)
#pragma unroll
            for (int kh = 0; kh < 2; kh++) {
                int fi = (dt * 2 + kh) * 64 + lane;
                uint4 H = WH[fi];
                uint4 L = WL[fi];
                WgH[dt][kh] = *(const bfrag*)&H;
                WgL[dt][kh] = *(const bfrag*)&L;
            }
    }
    __syncthreads();

    int n = n0 + wv;                             // wave = n
#pragma unroll
    for (int rt = 0; rt < 2; rt++) {             // s-half
        facc a0 = {0.f, 0.f, 0.f, 0.f};
        facc a1 = {0.f, 0.f, 0.f, 0.f};
        facc a2 = {0.f, 0.f, 0.f, 0.f};
        facc a3 = {0.f, 0.f, 0.f, 0.f};
#pragma unroll
        for (int kh = 0; kh < 2; kh++) {
            int row = wv * 32 + rt * 16 + l15;   // b-frag: col = row(n,s), k-grp = lg
            uint32_t off = (uint32_t)(row * 128 + kh * 64 + (lg << 4));
            off ^= (uint32_t)((row & 7) << 4);
            bfrag xh = *(const bfrag*)(Xhi + off);
            bfrag xl = *(const bfrag*)(Xlo + off);
            a0 = __builtin_amdgcn_mfma_f32_16x16x32_bf16(WgH[0][kh], xh, a0, 0, 0, 0);
            a1 = __builtin_amdgcn_mfma_f32_16x16x32_bf16(WgH[1][kh], xh, a1, 0, 0, 0);
            a2 = __builtin_amdgcn_mfma_f32_16x16x32_bf16(WgH[2][kh], xh, a2, 0, 0, 0);
            a3 = __builtin_amdgcn_mfma_f32_16x16x32_bf16(WgH[3][kh], xh, a3, 0, 0, 0);
            a0 = __builtin_amdgcn_mfma_f32_16x16x32_bf16(WgL[0][kh], xh, a0, 0, 0, 0);
            a1 = __builtin_amdgcn_mfma_f32_16x16x32_bf16(WgL[1][kh], xh, a1, 0, 0, 0);
            a2 = __builtin_amdgcn_mfma_f32_16x16x32_bf16(WgL[2][kh], xh, a2, 0, 0, 0);
            a3 = __builtin_amdgcn_mfma_f32_16x16x32_bf16(WgL[3][kh], xh, a3, 0, 0, 0);
            a0 = __builtin_amdgcn_mfma_f32_16x16x32_bf16(WgH[0][kh], xl, a0, 0, 0, 0);
            a1 = __builtin_amdgcn_mfma_f32_16x16x32_bf16(WgH[1][kh], xl, a1, 0, 0, 0);
            a2 = __builtin_amdgcn_mfma_f32_16x16x32_bf16(WgH[2][kh], xl, a2, 0, 0, 0);
            a3 = __builtin_amdgcn_mfma_f32_16x16x32_bf16(WgH[3][kh], xl, a3, 0, 0, 0);
        }
        // C/D: col = s-row = l15, row = d = dt*16 + lg*4 + reg
        int s = rt * 16 + l15;
        ushort* op = hw + (((size_t)(b * NN + n)) * SS + s) * CSP;
        {
            uint32_t p0 = f2b_rne(a0[0]) | (f2b_rne(a0[1]) << 16);
            uint32_t p1 = f2b_rne(a0[2]) | (f2b_rne(a0[3]) << 16);
            *(uint2*)(op + 0 * 16 + lg * 4) = make_uint2(p0, p1);
        }
        {
            uint32_t p0 = f2b_rne(a1[0]) | (f2b_rne(a1[1]) << 16);
            uint32_t p1 = f2b_rne(a1[2]) | (f2b_rne(a1[3]) << 16);
            *(uint2*)(op + 1 * 16 + lg * 4) = make_uint2(p0, p1);
        }
        {
            uint32_t p0 = f2b_rne(a2[0]) | (f2b_rne(a2[1]) << 16);
            uint32_t p1 = f2b_rne(a2[2]) | (f2b_rne(a2[3]) << 16);
            *(uint2*)(op + 2 * 16 + lg * 4) = make_uint2(p0, p1);
        }
        {
            uint32_t p0 = f2b_rne(a3[0]) | (f2b_rne(a3[1]) << 16);
            uint32_t p1 = f2b_rne(a3[2]) | (f2b_rne(a3[3]) << 16);
            *(uint2*)(op + 3 * 16 + lg * 4) = make_uint2(p0, p1);
        }
    }
}

// ---------- GCN aggregate v5: 4 nodes/block (R8 slab size) + 4-deep unroll ----
// R9 changed unroll AND block count together; net neutral because halving
// nodes/block doubled BN2 partial slabs (+33.6MB HBM rw ~ +5.3us) which ate
// the unroll's win. v5 keeps the 4-deep unroll at 1024 blocks/4 nodes.
__global__ __launch_bounds__(256, 4) void gcn_kernel(
    const ushort* __restrict__ hw, const int* __restrict__ row_ptr,
    const int2* __restrict__ edata, const float* __restrict__ dinv,
    const float* __restrict__ bg, float* __restrict__ agg,
    float* __restrict__ psum2, float* __restrict__ pss2) {
    int t = threadIdx.x;
    int blk = blockIdx.x;                   // 1024
    int xcd = blk & 7, jj = blk >> 3;       // b-per-XCD-pair locality heuristic
    int b = xcd >> 1;
    int grp = (xcd & 1) + 2 * jj;           // 0..255
    int n0 = grp * 4;
    int off = t * 8;                        // ushort offset within 2048-elem row
    const ushort* hwb = hw + (size_t)b * NN * 2048;
    float bgv[8];
    int c0 = off & 63;
#pragma unroll
    for (int j = 0; j < 8; j++) bgv[j] = bg[c0 + j];
    float sS[8], sQ[8];
#pragma unroll
    for (int j = 0; j < 8; j++) { sS[j] = 0.f; sQ[j] = 0.f; }
    for (int g = 0; g < 4; g++) {
        int n = n0 + g;
        int r0 = row_ptr[n], r1 = row_ptr[n + 1];
        float dn = dinv[n];
        float acc[8];
        {   // self row, weight dn
            uint4 u = *(const uint4*)(hwb + (size_t)n * 2048 + off);
            acc[0] = dn * bfu(u.x); acc[1] = dn * bfh(u.x);
            acc[2] = dn * bfu(u.y); acc[3] = dn * bfh(u.y);
            acc[4] = dn * bfu(u.z); acc[5] = dn * bfh(u.z);
            acc[6] = dn * bfu(u.w); acc[7] = dn * bfh(u.w);
        }
        int r = r0;
        for (; r + 4 <= r1; r += 4) {       // 4 rows in flight
            int2 e0 = edata[r], e1 = edata[r + 1];
            int2 e2 = edata[r + 2], e3 = edata[r + 3];
            uint4 u0 = *(const uint4*)(hwb + (size_t)e0.x * 2048 + off);
            uint4 u1 = *(const uint4*)(hwb + (size_t)e1.x * 2048 + off);
            uint4 u2 = *(const uint4*)(hwb + (size_t)e2.x * 2048 + off);
            uint4 u3 = *(const uint4*)(hwb + (size_t)e3.x * 2048 + off);
            float w0 = __int_as_float(e0.y), w1 = __int_as_float(e1.y);
            float w2 = __int_as_float(e2.y), w3 = __int_as_float(e3.y);
            acc[0] += w0 * bfu(u0.x) + w1 * bfu(u1.x);
            acc[1] += w0 * bfh(u0.x) + w1 * bfh(u1.x);
            acc[2] += w0 * bfu(u0.y) + w1 * bfu(u1.y);
            acc[3] += w0 * bfh(u0.y) + w1 * bfh(u1.y);
            acc[4] += w0 * bfu(u0.z) + w1 * bfu(u1.z);
            acc[5] += w0 * bfh(u0.z) + w1 * bfh(u1.z);
            acc[6] += w0 * bfu(u0.w) + w1 * bfu(u1.w);
            acc[7] += w0 * bfh(u0.w) + w1 * bfh(u1.w);
            acc[0] += w2 * bfu(u2.x) + w3 * bfu(u3.x);
            acc[1] += w2 * bfh(u2.x) + w3 * bfh(u3.x);
            acc[2] += w2 * bfu(u2.y) + w3 * bfu(u3.y);
            acc[3] += w2 * bfh(u2.y) + w3 * bfh(u3.y);
            acc[4] += w2 * bfu(u2.z) + w3 * bfu(u3.z);
            acc[5] += w2 * bfh(u2.z) + w3 * bfh(u3.z);
            acc[6] += w2 * bfu(u2.w) + w3 * bfu(u3.w);
            acc[7] += w2 * bfh(u2.w) + w3 * bfh(u3.w);
        }
        for (; r < r1; r++) {
            int2 e = edata[r];
            uint4 u = *(const uint4*)(hwb + (size_t)e.x * 2048 + off);
            float w = __int_as_float(e.y);
            acc[0] += w * bfu(u.x); acc[1] += w * bfh(u.x);
            acc[2] += w * bfu(u.y); acc[3] += w * bfh(u.y);
            acc[4] += w * bfu(u.z); acc[5] += w * bfh(u.z);
            acc[6] += w * bfu(u.w); acc[7] += w * bfh(u.w);
        }
        float o[8];
#pragma unroll
        for (int j = 0; j < 8; j++) {
            o[j] = dn * acc[j] + bgv[j];
            sS[j] += o[j]; sQ[j] += o[j] * o[j];
        }
        float* ar = agg + ((size_t)(b * NN + n)) * 2048 + off;
        float4 o0 = {o[0], o[1], o[2], o[3]}, o1 = {o[4], o[5], o[6], o[7]};
        *(float4*)ar = o0; *(float4*)(ar + 4) = o1;
    }
    float* ps = psum2 + ((size_t)(b * 256 + grp)) * 2048 + off;
    float* pq = pss2 + ((size_t)(b * 256 + grp)) * 2048 + off;
    float4 s0v = {sS[0], sS[1], sS[2], sS[3]}, s1v = {sS[4], sS[5], sS[6], sS[7]};
    float4 q0v = {sQ[0], sQ[1], sQ[2], sQ[3]}, q1v = {sQ[4], sQ[5], sQ[6], sQ[7]};
    *(float4*)ps = s0v; *(float4*)(ps + 4) = s1v;
    *(float4*)pq = q0v; *(float4*)(pq + 4) = q1v;
}

// ---------- BN2 reduce (R8-proven): 256 blocks, 8 threads/(b,s,c), 256 grp ----
__global__ __launch_bounds__(256) void bn2_reduce_kernel(
    const float* __restrict__ psum2, const float* __restrict__ pss2,
    const float* __restrict__ gs, const float* __restrict__ bes,
    float* __restrict__ scale2, float* __restrict__ shift2) {
    __shared__ float redS[4][32], redQ[4][32];
    int t = threadIdx.x;
    int slot = blockIdx.x * 32 + (t & 31);      // 256 blocks x 32 slots = 8192
    int b = slot >> 11, rem = slot & 2047;
    int chunk = t >> 5;                          // 0..7, 32 groups each
    const float* ps = psum2 + ((size_t)(b * 256 + chunk * 32)) * 2048 + rem;
    const float* pq = pss2 + ((size_t)(b * 256 + chunk * 32)) * 2048 + rem;
    float S = 0.f, Q = 0.f;
#pragma unroll 8
    for (int i = 0; i < 32; i++) {
        S += ps[(size_t)i * 2048];
        Q += pq[(size_t)i * 2048];
    }
    S += __shfl_down(S, 32);                     // chunk 2w+1 into 2w
    Q += __shfl_down(Q, 32);
    int w = t >> 6;
    if ((t & 63) < 32) { redS[w][t & 31] = S; redQ[w][t & 31] = Q; }
    __syncthreads();
    if (t < 32) {
        float Sf = redS[0][t] + redS[1][t] + redS[2][t] + redS[3][t];
        float Qf = redQ[0][t] + redQ[1][t] + redQ[2][t] + redQ[3][t];
        int slot0 = blockIdx.x * 32 + t;
        int d = slot0 & 63;
        float m = Sf * (1.f / NN);
        float v = Qf * (1.f / NN) - m * m;
        float sc = gs[d] * rsqrtf(v + EPSV);
        scale2[slot0] = sc;
        shift2[slot0] = bes[d] - m * sc;
    }
}

// ---------- conv2 via MFMA: BN2+ReLU -> hi/lo bf16 split -> 3-tap GEMM ----------
__global__ __launch_bounds__(256, 2) void conv2_mfma_kernel(
    const float* __restrict__ agg, const float* __restrict__ scale2,
    const float* __restrict__ shift2, const uint32_t* __restrict__ wpkH,
    const uint32_t* __restrict__ wpkL,
    const float* __restrict__ b2, float* __restrict__ h2_pre,
    float* __restrict__ psumC, float* __restrict__ pssC) {
    __shared__ __align__(16) char pool[35840];     // 17408 hi | 17408 lo | 1024 red
    char* Phi = pool;
    char* Plo = pool + 17408;
    float* redS = (float*)(pool + 34816);          // [4 waves][32]
    float* redQ = (float*)(pool + 35328);
    int t = threadIdx.x;
    int grp = blockIdx.x;                          // 1024 = b(4) x 256
    int b = grp >> 8, n0 = (grp & 255) * 4;
    int lane = t & 63, wv = t >> 6;
    int s0 = (wv >> 1) * 16, cb = (wv & 1) * 32;
    int l15 = lane & 15, lg = lane >> 4;

    // ---- zero halo rows (t=0 and t=33 of each n-tile), swizzled ----
    if (t < 128) {
        int nl = t >> 5, rem = t & 31;
        int tr = (rem >> 4) ? 33 : 0;
        int j = rem & 15;
        uint32_t off = (uint32_t)(nl * 4352 + tr * 128 + 8 * j);
        off ^= (uint32_t)((tr & 7) << 4);
        *(uint2*)(Phi + off) = make_uint2(0u, 0u);
        *(uint2*)(Plo + off) = make_uint2(0u, 0u);
    }
    // ---- stage agg with BN2+ReLU, hi/lo bf16 split, swizzled write ----
#pragma unroll
    for (int i = 0; i < 8; i++) {
        int flat4 = i * 256 + t;                   // 2048 float4s = 4n x 32s x 16 cquads
        int c0 = 4 * (flat4 & 15);
        int s = (flat4 >> 4) & 31;
        int nl = flat4 >> 9;
        const float* p = agg + ((size_t)((b * NN + n0 + nl) * 32 + s)) * 64 + c0;
        float4 u = *(const float4*)p;
        int bsi = (b * 32 + s) * 64 + c0;
        float4 sc = *(const float4*)(scale2 + bsi);
        float4 sh = *(const float4*)(shift2 + bsi);
        float v0 = fmaxf(u.x * sc.x + sh.x, 0.f);
        float v1 = fmaxf(u.y * sc.y + sh.y, 0.f);
        float v2 = fmaxf(u.z * sc.z + sh.z, 0.f);
        float v3 = fmaxf(u.w * sc.w + sh.w, 0.f);
        uint32_t h0 = f2b_rne(v0), h1 = f2b_rne(v1), h2 = f2b_rne(v2), h3 = f2b_rne(v3);
        uint32_t l0 = f2b_rne(v0 - bfu(h0)), l1 = f2b_rne(v1 - bfu(h1));
        uint32_t l2 = f2b_rne(v2 - bfu(h2)), l3 = f2b_rne(v3 - bfu(h3));
        int tr = s + 1;
        uint32_t off = (uint32_t)(nl * 4352 + tr * 128 + 2 * c0);
        off ^= (uint32_t)((tr & 7) << 4);
        *(uint2*)(Phi + off) = make_uint2(h0 | (h1 << 16), h2 | (h3 << 16));
        *(uint2*)(Plo + off) = make_uint2(l0 | (l1 << 16), l2 | (l3 << 16));
    }

    // ---- weight fragments: coalesced prepacked loads (L2-resident, 1KB/wave) ----
    bfrag Wh[2][3][2], Wl[2][3][2];
    {
        const uint4* WH = (const uint4*)wpkH;
        const uint4* WL = (const uint4*)wpkL;
        int cb2 = wv & 1;
#pragma unroll
        for (int ct = 0; ct < 2; ct++)
#pragma unroll
            for (int tap = 0; tap < 3; tap++)
#pragma unroll
                for (int kh = 0; kh < 2; kh++) {
                    int fi = ((((cb2 * 2 + ct) * 3 + tap) * 2) + kh) * 64 + lane;
                    uint4 H = WH[fi];
                    uint4 L = WL[fi];
                    Wh[ct][tap][kh] = *(const bfrag*)&H;
                    Wl[ct][tap][kh] = *(const bfrag*)&L;
                }
    }
    __syncthreads();

    float bb0 = b2[cb + l15], bb1 = b2[cb + 16 + l15];
    float sS0 = 0.f, sS1 = 0.f, sQ0 = 0.f, sQ1 = 0.f;
    for (int nl = 0; nl < 4; nl++) {
        facc acc0 = {0.f, 0.f, 0.f, 0.f};
        facc acc1 = {0.f, 0.f, 0.f, 0.f};
#pragma unroll
        for (int tap = 0; tap < 3; tap++) {
#pragma unroll
            for (int kh = 0; kh < 2; kh++) {
                int row = s0 + tap + l15;          // a-frag: lane = row l&15, k-grp l>>4
                uint32_t off = (uint32_t)(nl * 4352 + row * 128 + kh * 64 + (lg << 4));
                off ^= (uint32_t)((row & 7) << 4);
                bfrag ah = *(const bfrag*)(Phi + off);
                bfrag al = *(const bfrag*)(Plo + off);
                acc0 = __builtin_amdgcn_mfma_f32_16x16x32_bf16(ah, Wh[0][tap][kh], acc0, 0, 0, 0);
                acc1 = __builtin_amdgcn_mfma_f32_16x16x32_bf16(ah, Wh[1][tap][kh], acc1, 0, 0, 0);
                acc0 = __builtin_amdgcn_mfma_f32_16x16x32_bf16(al, Wh[0][tap][kh], acc0, 0, 0, 0);
                acc1 = __builtin_amdgcn_mfma_f32_16x16x32_bf16(al, Wh[1][tap][kh], acc1, 0, 0, 0);
                acc0 = __builtin_amdgcn_mfma_f32_16x16x32_bf16(ah, Wl[0][tap][kh], acc0, 0, 0, 0);
                acc1 = __builtin_amdgcn_mfma_f32_16x16x32_bf16(ah, Wl[1][tap][kh], acc1, 0, 0, 0);
            }
        }
        // epilogue: C/D layout col=lane&15 (cout), row=(lane>>4)*4+reg (s, contiguous)
        int sx = s0 + (lg << 2);
        float* hp = h2_pre + ((size_t)(b * NN + n0 + nl)) * (COUT * SS);
        {
            float y0 = acc0[0] + bb0, y1 = acc0[1] + bb0;
            float y2 = acc0[2] + bb0, y3 = acc0[3] + bb0;
            float4 o = {y0, y1, y2, y3};
            *(float4*)(hp + (cb + l15) * SS + sx) = o;
            sS0 += y0 + y1 + y2 + y3;
            sQ0 += y0 * y0 + y1 * y1 + y2 * y2 + y3 * y3;
        }
        {
            float y0 = acc1[0] + bb1, y1 = acc1[1] + bb1;
            float y2 = acc1[2] + bb1, y3 = acc1[3] + bb1;
            float4 o = {y0, y1, y2, y3};
            *(float4*)(hp + (cb + 16 + l15) * SS + sx) = o;
            sS1 += y0 + y1 + y2 + y3;
            sQ1 += y0 * y0 + y1 * y1 + y2 * y2 + y3 * y3;
        }
    }
    // lanes {l, l+16, l+32, l+48} share a cout -> shfl reduce
    sS0 += __shfl_down(sS0, 16); sS0 += __shfl_down(sS0, 32);
    sS1 += __shfl_down(sS1, 16); sS1 += __shfl_down(sS1, 32);
    sQ0 += __shfl_down(sQ0, 16); sQ0 += __shfl_down(sQ0, 32);
    sQ1 += __shfl_down(sQ1, 16); sQ1 += __shfl_down(sQ1, 32);
    if (lane < 16) {
        redS[wv * 32 + lane] = sS0;      redQ[wv * 32 + lane] = sQ0;
        redS[wv * 32 + 16 + lane] = sS1; redQ[wv * 32 + 16 + lane] = sQ1;
    }
    __syncthreads();
    if (t < 64) {                                  // waves {wA, wA+2} share couts; c == t
        int wA = t >> 5, slot = t & 31;
        float S = redS[wA * 32 + slot] + redS[(wA + 2) * 32 + slot];
        float Q = redQ[wA * 32 + slot] + redQ[(wA + 2) * 32 + slot];
        psumC[(size_t)t * 1024 + grp] = S;         // [c][1024] slab, no RMW contention
        pssC[(size_t)t * 1024 + grp] = Q;
    }
}

// ---------- final: BN3+ReLU + residual 1x1 conv + ReLU, write [B,Cout,N,S] ----------
__global__ __launch_bounds__(256) void final_kernel(
    const float* __restrict__ x, const float* __restrict__ Wres,
    const float* __restrict__ bres, const float* __restrict__ h2_pre,
    const float* __restrict__ scale3, const float* __restrict__ shift3,
    float* __restrict__ out) {
    __shared__ __align__(16) float xs[CIN][36];
    __shared__ float wrl[COUT * 33];
    int t = threadIdx.x;
    int bn = blockIdx.x;
    int b = bn >> 10, n = bn & (NN - 1);
    {
        int sst = t & 31, cinb = t >> 5;            // bank 2-way
#pragma unroll
        for (int i = 0; i < 4; i++) {
            int cin = cinb + 8 * i;
            xs[cin][sst] = x[(((size_t)b * CIN + cin) * NN + n) * SS + sst];
        }
    }
#pragma unroll
    for (int i = 0; i < 2; i++) {
        int lin = (i * 256 + t) * 4;                // rows of 32
        int cw = lin >> 5, c0 = lin & 31;
        float4 v = *(const float4*)(Wres + lin);
        float* dst = &wrl[cw * 33 + c0];
        dst[0] = v.x; dst[1] = v.y; dst[2] = v.z; dst[3] = v.w;
    }
    __syncthreads();
    int cout = t >> 2, s0 = (t & 3) * 8;
    float res[8];
    float bb = bres[cout];
#pragma unroll
    for (int j = 0; j < 8; j++) res[j] = bb;
    const float* wrow = &wrl[cout * 33];
#pragma unroll 4
    for (int cin = 0; cin < CIN; cin++) {
        float w = wrow[cin];
        float4 xa = *(const float4*)&xs[cin][s0];
        float4 xb = *(const float4*)&xs[cin][s0 + 4];
        res[0] += xa.x * w; res[1] += xa.y * w; res[2] += xa.z * w; res[3] += xa.w * w;
        res[4] += xb.x * w; res[5] += xb.y * w; res[6] += xb.z * w; res[7] += xb.w * w;
    }
    const float* hp = h2_pre + (size_t)bn * COUT * SS + cout * SS + s0;
    float4 h0 = *(const float4*)hp, h1 = *(const float4*)(hp + 4);
    float h2[8] = {h0.x, h0.y, h0.z, h0.w, h1.x, h1.y, h1.z, h1.w};
    float sc = scale3[cout], sh = shift3[cout];
    float o[8];
#pragma unroll
    for (int j = 0; j < 8; j++) {
        float hv = fmaxf(sc * h2[j] + sh, 0.f);
        o[j] = fmaxf(hv + res[j], 0.f);
    }
    float* op = out + (((size_t)b * COUT + cout) * NN + n) * SS + s0;
    float4 o0 = {o[0], o[1], o[2], o[3]}, o1 = {o[4], o[5], o[6], o[7]};
    *(float4*)op = o0; *(float4*)(op + 4) = o1;
}

// ---------- host ----------
extern "C" void kernel_launch(void* const* d_in, const int* in_sizes, int n_in,
                              void* d_out, int out_size, void* d_ws, size_t ws_size,
                              hipStream_t stream) {
    const float* x    = (const float*)d_in[0];
    const int*   ei   = (const int*)  d_in[1];
    const float* W1   = (const float*)d_in[2];
    const float* b1   = (const float*)d_in[3];
    const float* g1   = (const float*)d_in[4];
    const float* be1  = (const float*)d_in[5];
    const float* Wg   = (const float*)d_in[6];
    const float* bg   = (const float*)d_in[7];
    const float* gs   = (const float*)d_in[8];
    const float* bes  = (const float*)d_in[9];
    const float* W2   = (const float*)d_in[10];
    const float* b2   = (const float*)d_in[11];
    const float* g2   = (const float*)d_in[12];
    const float* be2  = (const float*)d_in[13];
    const float* Wres = (const float*)d_in[14];
    const float* bres = (const float*)d_in[15];
    float* out = (float*)d_out;
    int E = in_sizes[1] / 2;

    char* ws = (char*)d_ws;
    int*   deg    = (int*)  (ws + 0);            // 4096 B (zeroed by pack_zero)
    int*   cursor = (int*)  (ws + 4096);         // 4096 B (zeroed by pack_zero)
    uint32_t* wpkH = (uint32_t*)(ws + 8192);     // 24576 B (packed W2 hi frags)
    uint32_t* wpkL = (uint32_t*)(ws + 32768);    // 24576 B -> 57344 (< 73728)
    int*   row_ptr= (int*)  (ws + 73728);        // 4100 B
    float* dinv   = (float*)(ws + 78080);        // 4096 B
    float* scale1 = (float*)(ws + 82176);        // 256 B each
    float* shift1 = (float*)(ws + 82432);
    float* scale3 = (float*)(ws + 82688);
    float* shift3 = (float*)(ws + 82944);
    float* scale2 = (float*)(ws + 83200);        // 32768 B
    float* shift2 = (float*)(ws + 115968);       // 32768 B -> 148736
    int2*  edata  = (int2*) (ws + 410880);       // 8*E = 131072 B -> 541952
    char*  bigA   = ws + 542720;                 // 33.55 MB region
    ushort* hwB   = (ushort*)bigA;
    float* h2p    = (float*)bigA;
    // BN-stat slabs + packed weight frags (beyond bigA's 33.55MB)
    float* psumC  = (float*)(ws + 34097152);     // 262144 B (64 ch x 1024 grp)
    float* pssC   = (float*)(ws + 34359296);     // 262144 B -> 34621440
    uint32_t* wpk1H = (uint32_t*)(ws + 34621440);// 12288 B (packed W1 hi frags)
    uint32_t* wpk1L = (uint32_t*)(ws + 34633728);// 12288 B -> 34646016
    uint32_t* wgpH  = (uint32_t*)(ws + 34646016);// 8192 B (packed Wg^T hi frags)
    uint32_t* wgpL  = (uint32_t*)(ws + 34654208);// 8192 B -> 34662400
    // BN2 partial slabs (8.39 MB each at 256 groups; region reserved to 69MB)
    float* psum2  = (float*)(ws + 35651584);     // -> 44040192 used
    float* pss2   = (float*)(ws + 52428800);     // -> 60817408 used
    // d_out doubles as scratch: h_pre (conv1 out), then agg (gcn out).
    float* h_pre  = out;
    float* agg    = out;

    pack_zero_kernel<<<12, 256, 0, stream>>>(W1, W2, Wg, wpk1H, wpk1L,
                                             wpkH, wpkL, wgpH, wgpL, deg, cursor);
    int egrid = (E + 255) / 256;
    deg_count_kernel<<<egrid, 256, 0, stream>>>(ei, E, deg);
    scan_kernel<<<1, NN, 0, stream>>>(deg, row_ptr, dinv);
    csr_fill_kernel<<<egrid, 256, 0, stream>>>(ei, E, row_ptr, cursor, dinv, edata);

    conv1_mfma_kernel<<<1024, 256, 0, stream>>>(x, wpk1H, wpk1L, b1, h_pre, psumC, pssC);
    bn_reduce_kernel<<<64, 256, 0, stream>>>(psumC, pssC, g1, be1, scale1, shift1,
                                             1.f / (B_ * NN * SS), 1024, 1024);
    bn1_gemm_mfma_kernel<<<1024, 256, 0, stream>>>(h_pre, scale1, shift1, wgpH, wgpL, hwB);
    gcn_kernel<<<1024, 256, 0, stream>>>(hwB, row_ptr, edata, dinv, bg, agg, psum2, pss2);
    bn2_reduce_kernel<<<256, 256, 0, stream>>>(psum2, pss2, gs, bes, scale2, shift2);
    conv2_mfma_kernel<<<1024, 256, 0, stream>>>(agg, scale2, shift2, wpkH, wpkL,
                                                b2, h2p, psumC, pssC);
    bn_reduce_kernel<<<64, 256, 0, stream>>>(psumC, pssC, g2, be2, scale3, shift3,
                                             1.f / (B_ * NN * SS), 1024, 1024);
    final_kernel<<<B_ * NN, 256, 0, stream>>>(x, Wres, bres, h2p, scale3, shift3, out);
}